// Round 5
// baseline (491.948 us; speedup 1.0000x reference)
//
#include <hip/hip_runtime.h>
#include <cmath>

#define NPTS 8192
#define DIM 64
#define BT 128          // tile dimension
#define LDSK 129        // padded k-row stride for As/Bs
#define KSTR 132        // padded row stride for the k-value tile (2-way max conflicts)
#define SMEMW 16896     // max(2*64*129, 128*132) words

// ws layout (floats):
//  [0 .. LEAF_FLOATS)            : leaf sums, [(z*8192 + row)*64 + cb]   (6 MB)
//  [LEAF_FLOATS .. +ROW_FLOATS)  : row sums,  [z*8192 + row]             (96 KB)
//  [LEAF_FLOATS+ROW_FLOATS .. +3): fp32 means per matrix
#define LEAF_FLOATS (3 * 8192 * 64)
#define ROW_FLOATS  (3 * 8192)

__global__ __launch_bounds__(256, 2) void mmd_tile_kernel(
    const float* __restrict__ x, const float* __restrict__ y,
    float* __restrict__ leafs)
{
    __shared__ float smem[SMEMW];
    __shared__ float sqA[BT];
    __shared__ float sqB[BT];

    float (*As)[LDSK] = (float(*)[LDSK])smem;                 // [64][129]
    float (*Bs)[LDSK] = (float(*)[LDSK])(smem + DIM * LDSK);  // [64][129]
    float (*Ks)[KSTR] = (float(*)[KSTR])smem;                 // [128][132], aliases As/Bs

    const int t = threadIdx.x;
    const int z = blockIdx.z;              // 0: k(x,x), 1: k(y,y), 2: k(x,y)
    const float* Ap = (z == 1) ? y : x;
    const float* Bp = (z == 0) ? x : y;

    const size_t arow = (size_t)blockIdx.y * BT;   // row offset   (i index)
    const size_t brow = (size_t)blockIdx.x * BT;   // col offset   (j index)
    const int cb = blockIdx.x;                     // 128-col leaf-block index

    // ---- stage 128x64 tiles, global row-major -> LDS k-major
    {
        const float4* Ag = (const float4*)(Ap + arow * DIM);
        const float4* Bg = (const float4*)(Bp + brow * DIM);
        #pragma unroll
        for (int it = 0; it < 8; ++it) {
            int e  = it * 256 + t;
            int r  = e >> 4;
            int kb = (e & 15) << 2;
            float4 va = Ag[e];
            float4 vb = Bg[e];
            As[kb+0][r] = va.x; As[kb+1][r] = va.y; As[kb+2][r] = va.z; As[kb+3][r] = va.w;
            Bs[kb+0][r] = vb.x; Bs[kb+1][r] = vb.y; Bs[kb+2][r] = vb.z; Bs[kb+3][r] = vb.w;
        }
    }
    __syncthreads();

    // ---- per-row squared norms from LDS
    {
        int w = t >> 6;
        int r = ((w & 1) << 6) | (t & 63);
        float s = 0.f;
        if (w < 2) {
            #pragma unroll
            for (int k = 0; k < DIM; ++k) { float v = As[k][r]; s = fmaf(v, v, s); }
            sqA[r] = s;
        } else {
            #pragma unroll
            for (int k = 0; k < DIM; ++k) { float v = Bs[k][r]; s = fmaf(v, v, s); }
            sqB[r] = s;
        }
    }
    __syncthreads();

    // ---- 8x8 micro-tile per thread, stride-16 rows/cols
    const int tx = t & 15;
    const int ty = t >> 4;

    float acc[8][8];
    #pragma unroll
    for (int m = 0; m < 8; ++m)
        #pragma unroll
        for (int n = 0; n < 8; ++n) acc[m][n] = 0.f;

    #pragma unroll 4
    for (int k = 0; k < DIM; ++k) {
        float a[8], b[8];
        #pragma unroll
        for (int m = 0; m < 8; ++m) a[m] = As[k][ty + 16 * m];
        #pragma unroll
        for (int n = 0; n < 8; ++n) b[n] = Bs[k][tx + 16 * n];
        #pragma unroll
        for (int m = 0; m < 8; ++m)
            #pragma unroll
            for (int n = 0; n < 8; ++n)
                acc[m][n] = fmaf(a[m], b[n], acc[m][n]);
    }

    float sa[8], sb[8];
    #pragma unroll
    for (int m = 0; m < 8; ++m) sa[m] = sqA[ty + 16 * m];
    #pragma unroll
    for (int n = 0; n < 8; ++n) sb[n] = sqB[tx + 16 * n];

    __syncthreads();   // all As/Bs reads done; Ks may now overwrite them

    // ---- k-values, replicating np per-element math:
    //   sq_dist = (sq_a + sq_b) - 2*ab ; arg = -sq_dist/4096 (exact) ; expf ~ np.exp
    const float NSCL = -1.0f / 4096.0f;   // -2^-12, exact
    #pragma unroll
    for (int m = 0; m < 8; ++m)
        #pragma unroll
        for (int n = 0; n < 8; ++n) {
            float s2  = sa[m] + sb[n];
            float sqd = s2 - 2.0f * acc[m][n];   // fma-contraction is bit-identical (2*acc exact)
            Ks[ty + 16 * m][tx + 16 * n] = expf(sqd * NSCL);
        }
    __syncthreads();

    // ---- numpy leaf sums: per (row, t in 0..7): r[t] = Ks[row][t] + sum_q Ks[row][t+8q]
    //      then ((r0+r1)+(r2+r3))+((r4+r5)+(r6+r7)) via shfl_xor (fp32 add is commutative)
    float leaf[4];
    #pragma unroll
    for (int j = 0; j < 4; ++j) {
        int ch  = t + 256 * j;        // chain id 0..1023
        int row = ch >> 3;
        int tt  = ch & 7;
        float s = Ks[row][tt];
        #pragma unroll
        for (int q = 1; q < 16; ++q) s += Ks[row][tt + 8 * q];
        float p;
        p = __shfl_xor(s, 1); s = s + p;   // (r0+r1), (r2+r3), ...
        p = __shfl_xor(s, 2); s = s + p;   // ((r0+r1)+(r2+r3)), ...
        p = __shfl_xor(s, 4); s = s + p;   // full leaf sum
        leaf[j] = s;
    }
    if ((t & 7) == 0) {
        int rbase = t >> 3;               // 0..31
        #pragma unroll
        for (int j = 0; j < 4; ++j) {
            int row = rbase + 32 * j;
            leafs[((size_t)z * 8192 + arow + row) * 64 + cb] = leaf[j];
        }
    }
}

// Phase B: per row, balanced binary tree over its 64 leaf sums (= numpy's tree
// levels between 128-blocks and full rows; 8192 = 128*64, all power-of-2 splits)
__global__ void rowsum_kernel(const float* __restrict__ leafs, float* __restrict__ rowsums) {
    int tid = blockIdx.x * 256 + threadIdx.x;    // 0 .. 3*8192-1
    const float4* p = (const float4*)(leafs + (size_t)tid * 64);
    float v[64];
    #pragma unroll
    for (int i = 0; i < 16; ++i) {
        float4 q = p[i];
        v[4*i+0] = q.x; v[4*i+1] = q.y; v[4*i+2] = q.z; v[4*i+3] = q.w;
    }
    #pragma unroll
    for (int n = 32; n >= 1; n >>= 1)
        #pragma unroll
        for (int i = 0; i < 64; ++i)       // guard inside: compiler unrolls cleanly
            if (i < n) v[i] = v[2*i] + v[2*i+1];
    rowsums[tid] = v[0];
}

// Phase C: per matrix, balanced tree over 8192 row sums; mean = sum / 2^26 (exact)
__global__ void colsum_kernel(const float* __restrict__ rowsums, float* __restrict__ means) {
    __shared__ float A[8192];
    __shared__ float B[4096];
    const int z = blockIdx.x;
    const int t = threadIdx.x;
    const float* src = rowsums + z * 8192;
    for (int i = t; i < 8192; i += 256) A[i] = src[i];
    __syncthreads();
    float* cur = A;
    float* nxt = B;
    for (int n = 4096; n >= 1; n >>= 1) {
        for (int i = t; i < n; i += 256) nxt[i] = cur[2*i] + cur[2*i+1];
        __syncthreads();
        float* tmp = cur; cur = nxt; nxt = tmp;
    }
    if (t == 0) means[z] = cur[0] * (1.0f / 67108864.0f);   // exact pow-2 scale
}

// Phase D: fp32 combine in the reference's expression order
__global__ void combine_kernel(const float* __restrict__ means, float* __restrict__ out) {
    float t1 = means[0] + means[1];
    out[0] = t1 - 2.0f * means[2];
}

extern "C" void kernel_launch(void* const* d_in, const int* in_sizes, int n_in,
                              void* d_out, int out_size, void* d_ws, size_t ws_size,
                              hipStream_t stream) {
    const float* x = (const float*)d_in[0];
    const float* y = (const float*)d_in[1];
    float* leafs   = (float*)d_ws;
    float* rowsums = leafs + LEAF_FLOATS;
    float* means   = rowsums + ROW_FLOATS;

    dim3 grid(NPTS / BT, NPTS / BT, 3);
    mmd_tile_kernel<<<grid, 256, 0, stream>>>(x, y, leafs);
    rowsum_kernel<<<(3 * 8192) / 256, 256, 0, stream>>>(leafs, rowsums);
    colsum_kernel<<<3, 256, 0, stream>>>(rowsums, means);
    combine_kernel<<<1, 1, 0, stream>>>(means, (float*)d_out);
}

// Round 6
// 456.674 us; speedup vs baseline: 1.0772x; 1.0772x over previous
//
#include <hip/hip_runtime.h>
#include <cmath>

#define NPTS 8192
#define DIM 64
#define BT 128          // tile dimension
#define F4STR 130       // float4 row stride for As4/Bs4 (k4-major)
#define KSTR 136        // word stride for Ks rows: bank=(8*row+col)%32 -> uniform 2-way
#define SMEMW (128 * KSTR)   // 17408 words; >= 2*16*F4STR*4 = 16640 words for As4+Bs4

// ws layout (floats):
#define LEAF_FLOATS (3 * 8192 * 64)
#define ROW_FLOATS  (3 * 8192)

__global__ __launch_bounds__(256, 2) void mmd_tile_kernel(
    const float* __restrict__ x, const float* __restrict__ y,
    float* __restrict__ leafs)
{
    __shared__ __align__(16) float smem[SMEMW];
    __shared__ float sqA[BT];
    __shared__ float sqB[BT];

    float4* As4 = (float4*)smem;            // [16][F4STR] float4s: As4[k4][row]
    float4* Bs4 = As4 + 16 * F4STR;         // same shape
    float*  Ks  = smem;                     // [128][KSTR] floats, aliases As4/Bs4

    const int t = threadIdx.x;
    const int z = blockIdx.z;              // 0: k(x,x), 1: k(y,y), 2: k(x,y)
    const float* Ap = (z == 1) ? y : x;
    const float* Bp = (z == 0) ? x : y;

    const size_t arow = (size_t)blockIdx.y * BT;   // row offset (i)
    const size_t brow = (size_t)blockIdx.x * BT;   // col offset (j)
    const int cb = blockIdx.x;                     // 128-col leaf-block index

    // ---- stage 128x64 tiles: global float4 (= 4 consecutive k of one row)
    //      -> As4[k4][row], one ds_write_b128 each
    {
        const float4* Ag = (const float4*)(Ap + arow * DIM);
        const float4* Bg = (const float4*)(Bp + brow * DIM);
        #pragma unroll
        for (int it = 0; it < 8; ++it) {
            int e  = it * 256 + t;
            int r  = e >> 4;           // row within tile
            int k4 = e & 15;           // float4 index along k
            As4[k4 * F4STR + r] = Ag[e];
            Bs4[k4 * F4STR + r] = Bg[e];
        }
    }
    __syncthreads();

    // ---- per-row squared norms (k ascending via x,y,z,w -> identical chain)
    {
        int w = t >> 6;
        int r = ((w & 1) << 6) | (t & 63);
        float s = 0.f;
        if (w < 2) {
            #pragma unroll
            for (int k4 = 0; k4 < 16; ++k4) {
                float4 v = As4[k4 * F4STR + r];
                s = fmaf(v.x, v.x, s); s = fmaf(v.y, v.y, s);
                s = fmaf(v.z, v.z, s); s = fmaf(v.w, v.w, s);
            }
            sqA[r] = s;
        } else {
            #pragma unroll
            for (int k4 = 0; k4 < 16; ++k4) {
                float4 v = Bs4[k4 * F4STR + r];
                s = fmaf(v.x, v.x, s); s = fmaf(v.y, v.y, s);
                s = fmaf(v.z, v.z, s); s = fmaf(v.w, v.w, s);
            }
            sqB[r] = s;
        }
    }
    __syncthreads();

    // ---- 8x8 micro-tile per thread, stride-16 rows/cols; b128 fragment loads
    const int tx = t & 15;
    const int ty = t >> 4;

    float acc[8][8];
    #pragma unroll
    for (int m = 0; m < 8; ++m)
        #pragma unroll
        for (int n = 0; n < 8; ++n) acc[m][n] = 0.f;

    #pragma unroll 2
    for (int k4 = 0; k4 < 16; ++k4) {
        float4 a4[8], b4[8];
        #pragma unroll
        for (int m = 0; m < 8; ++m) a4[m] = As4[k4 * F4STR + ty + 16 * m];
        #pragma unroll
        for (int n = 0; n < 8; ++n) b4[n] = Bs4[k4 * F4STR + tx + 16 * n];
        // k = 4*k4 + kk ascending: same per-acc fma chain as scalar version
        #pragma unroll
        for (int kk = 0; kk < 4; ++kk) {
            #pragma unroll
            for (int m = 0; m < 8; ++m) {
                float av = ((const float*)&a4[m])[kk];
                #pragma unroll
                for (int n = 0; n < 8; ++n)
                    acc[m][n] = fmaf(av, ((const float*)&b4[n])[kk], acc[m][n]);
            }
        }
    }

    float sa[8], sb[8];
    #pragma unroll
    for (int m = 0; m < 8; ++m) sa[m] = sqA[ty + 16 * m];
    #pragma unroll
    for (int n = 0; n < 8; ++n) sb[n] = sqB[tx + 16 * n];

    __syncthreads();   // all As4/Bs4 reads done; Ks may overwrite

    // ---- k-values, identical per-element math to the passing round
    const float NSCL = -1.0f / 4096.0f;   // -2^-12, exact
    #pragma unroll
    for (int m = 0; m < 8; ++m)
        #pragma unroll
        for (int n = 0; n < 8; ++n) {
            float s2  = sa[m] + sb[n];
            float sqd = s2 - 2.0f * acc[m][n];
            Ks[(ty + 16 * m) * KSTR + (tx + 16 * n)] = expf(sqd * NSCL);
        }
    __syncthreads();

    // ---- numpy leaf sums (identical chain + shfl tree as passing round)
    float leaf[4];
    #pragma unroll
    for (int j = 0; j < 4; ++j) {
        int ch  = t + 256 * j;        // chain id 0..1023
        int row = ch >> 3;
        int tt  = ch & 7;
        float s = Ks[row * KSTR + tt];
        #pragma unroll
        for (int q = 1; q < 16; ++q) s += Ks[row * KSTR + tt + 8 * q];
        float p;
        p = __shfl_xor(s, 1); s = s + p;
        p = __shfl_xor(s, 2); s = s + p;
        p = __shfl_xor(s, 4); s = s + p;
        leaf[j] = s;
    }
    if ((t & 7) == 0) {
        int rbase = t >> 3;
        #pragma unroll
        for (int j = 0; j < 4; ++j) {
            int row = rbase + 32 * j;
            leafs[((size_t)z * 8192 + arow + row) * 64 + cb] = leaf[j];
        }
    }
}

// Phase B: per row, balanced binary tree over its 64 leaf sums
__global__ void rowsum_kernel(const float* __restrict__ leafs, float* __restrict__ rowsums) {
    int tid = blockIdx.x * 256 + threadIdx.x;    // 0 .. 3*8192-1
    const float4* p = (const float4*)(leafs + (size_t)tid * 64);
    float v[64];
    #pragma unroll
    for (int i = 0; i < 16; ++i) {
        float4 q = p[i];
        v[4*i+0] = q.x; v[4*i+1] = q.y; v[4*i+2] = q.z; v[4*i+3] = q.w;
    }
    #pragma unroll
    for (int n = 32; n >= 1; n >>= 1)
        #pragma unroll
        for (int i = 0; i < 64; ++i)
            if (i < n) v[i] = v[2*i] + v[2*i+1];
    rowsums[tid] = v[0];
}

// Phase C: per matrix, balanced tree over 8192 row sums; /2^26 exact
__global__ void colsum_kernel(const float* __restrict__ rowsums, float* __restrict__ means) {
    __shared__ float A[8192];
    __shared__ float B[4096];
    const int z = blockIdx.x;
    const int t = threadIdx.x;
    const float* src = rowsums + z * 8192;
    for (int i = t; i < 8192; i += 256) A[i] = src[i];
    __syncthreads();
    float* cur = A;
    float* nxt = B;
    for (int n = 4096; n >= 1; n >>= 1) {
        for (int i = t; i < n; i += 256) nxt[i] = cur[2*i] + cur[2*i+1];
        __syncthreads();
        float* tmp = cur; cur = nxt; nxt = tmp;
    }
    if (t == 0) means[z] = cur[0] * (1.0f / 67108864.0f);
}

// Phase D: fp32 combine in reference expression order
__global__ void combine_kernel(const float* __restrict__ means, float* __restrict__ out) {
    float t1 = means[0] + means[1];
    out[0] = t1 - 2.0f * means[2];
}

extern "C" void kernel_launch(void* const* d_in, const int* in_sizes, int n_in,
                              void* d_out, int out_size, void* d_ws, size_t ws_size,
                              hipStream_t stream) {
    const float* x = (const float*)d_in[0];
    const float* y = (const float*)d_in[1];
    float* leafs   = (float*)d_ws;
    float* rowsums = leafs + LEAF_FLOATS;
    float* means   = rowsums + ROW_FLOATS;

    dim3 grid(NPTS / BT, NPTS / BT, 3);
    mmd_tile_kernel<<<grid, 256, 0, stream>>>(x, y, leafs);
    rowsum_kernel<<<(3 * 8192) / 256, 256, 0, stream>>>(leafs, rowsums);
    colsum_kernel<<<3, 256, 0, stream>>>(rowsums, means);
    combine_kernel<<<1, 1, 0, stream>>>(means, (float*)d_out);
}

// Round 8
// 277.992 us; speedup vs baseline: 1.7696x; 1.6428x over previous
//
#include <hip/hip_runtime.h>
#include <cmath>

#define NPTS 8192
#define DIM 64
#define BT 128
#define RSTR 72          // bf16-element row stride for hi/lo tiles (36 words: conflict-free b128 frags)
#define KSTR 132         // float word stride for Ks rows (conflict-free C-layout writes)

#define LEAF_FLOATS (3 * 8192 * 64)
#define ROW_FLOATS  (3 * 8192)

typedef short bf16x8 __attribute__((ext_vector_type(8)));
typedef float f32x4  __attribute__((ext_vector_type(4)));

__device__ __forceinline__ unsigned short f32_bf16_rne(float f) {
    unsigned u = __float_as_uint(f);
    return (unsigned short)((u + 0x7FFFu + ((u >> 16) & 1u)) >> 16);
}
__device__ __forceinline__ float bf16_f32(unsigned short h) {
    return __uint_as_float(((unsigned)h) << 16);
}

__global__ __launch_bounds__(256, 2) void mmd_tile_kernel(
    const float* __restrict__ x, const float* __restrict__ y,
    float* __restrict__ leafs)
{
    __shared__ __align__(16) unsigned short smem[4 * BT * RSTR];  // 73728 B
    __shared__ float sqA[BT];
    __shared__ float sqB[BT];

    unsigned short* Ah = smem;
    unsigned short* Al = smem + 1 * BT * RSTR;
    unsigned short* Bh = smem + 2 * BT * RSTR;
    unsigned short* Bl = smem + 3 * BT * RSTR;
    float* Ks = (float*)smem;     // [128][KSTR] floats, aliases the bf16 tiles

    const int t = threadIdx.x;
    const int z = blockIdx.z;              // 0: k(x,x), 1: k(y,y), 2: k(x,y)
    const float* Ap = (z == 1) ? y : x;
    const float* Bp = (z == 0) ? x : y;

    const size_t arow = (size_t)blockIdx.y * BT;
    const size_t brow = (size_t)blockIdx.x * BT;
    const int cb = blockIdx.x;

    // ---- stage 128x64 fp32 tiles -> bf16 hi/lo tiles in LDS (RNE 2-term split)
    {
        const float4* Ag = (const float4*)(Ap + arow * DIM);
        const float4* Bg = (const float4*)(Bp + brow * DIM);
        #pragma unroll
        for (int it = 0; it < 8; ++it) {
            int e  = it * 256 + t;
            int r  = e >> 4;
            int k4 = e & 15;
            float4 va = Ag[e], vb = Bg[e];
            ushort4 ah, al, bh, bl;
            ah.x = f32_bf16_rne(va.x); al.x = f32_bf16_rne(va.x - bf16_f32(ah.x));
            ah.y = f32_bf16_rne(va.y); al.y = f32_bf16_rne(va.y - bf16_f32(ah.y));
            ah.z = f32_bf16_rne(va.z); al.z = f32_bf16_rne(va.z - bf16_f32(ah.z));
            ah.w = f32_bf16_rne(va.w); al.w = f32_bf16_rne(va.w - bf16_f32(ah.w));
            bh.x = f32_bf16_rne(vb.x); bl.x = f32_bf16_rne(vb.x - bf16_f32(bh.x));
            bh.y = f32_bf16_rne(vb.y); bl.y = f32_bf16_rne(vb.y - bf16_f32(bh.y));
            bh.z = f32_bf16_rne(vb.z); bl.z = f32_bf16_rne(vb.z - bf16_f32(bh.z));
            bh.w = f32_bf16_rne(vb.w); bl.w = f32_bf16_rne(vb.w - bf16_f32(bh.w));
            int o = r * RSTR + k4 * 4;
            *(ushort4*)(Ah + o) = ah;
            *(ushort4*)(Al + o) = al;
            *(ushort4*)(Bh + o) = bh;
            *(ushort4*)(Bl + o) = bl;
        }
    }

    // ---- per-row squared norms from GLOBAL fp32 (bitwise-identical chain to
    //      the passing rounds: k-ascending fma via float4 x,y,z,w)
    {
        int rid = t & 127;
        const float4* Rg = (const float4*)((t < BT) ? (Ap + (arow + rid) * DIM)
                                                    : (Bp + (brow + rid) * DIM));
        float s = 0.f;
        #pragma unroll
        for (int k4 = 0; k4 < 16; ++k4) {
            float4 v = Rg[k4];
            s = fmaf(v.x, v.x, s); s = fmaf(v.y, v.y, s);
            s = fmaf(v.z, v.z, s); s = fmaf(v.w, v.w, s);
        }
        if (t < BT) sqA[rid] = s; else sqB[rid] = s;
    }
    __syncthreads();

    // ---- MFMA main: wave w owns rows [32w,32w+32); 2 row-tiles x 8 col-tiles
    const int lane = t & 63;
    const int wv   = t >> 6;
    const int mrow = lane & 15;
    const int quad = lane >> 4;
    const int rbase = wv * 32;

    bf16x8 fAh[2][2], fAl[2][2];
    #pragma unroll
    for (int rt = 0; rt < 2; ++rt)
        #pragma unroll
        for (int kc = 0; kc < 2; ++kc) {
            const unsigned short* p = Ah + (rbase + rt * 16 + mrow) * RSTR + kc * 32 + quad * 8;
            fAh[rt][kc] = *(const bf16x8*)p;
            fAl[rt][kc] = *(const bf16x8*)(p + BT * RSTR);
        }

    f32x4 acc[2][8];
    #pragma unroll
    for (int rt = 0; rt < 2; ++rt)
        #pragma unroll
        for (int ct = 0; ct < 8; ++ct)
            acc[rt][ct] = (f32x4){0.f, 0.f, 0.f, 0.f};

    #pragma unroll
    for (int ct = 0; ct < 8; ++ct) {
        const unsigned short* q = Bh + (ct * 16 + mrow) * RSTR + quad * 8;
        bf16x8 bh0 = *(const bf16x8*)(q);
        bf16x8 bh1 = *(const bf16x8*)(q + 32);
        bf16x8 bl0 = *(const bf16x8*)(q + BT * RSTR);
        bf16x8 bl1 = *(const bf16x8*)(q + BT * RSTR + 32);
        #pragma unroll
        for (int rt = 0; rt < 2; ++rt) {
            f32x4 c = acc[rt][ct];
            c = __builtin_amdgcn_mfma_f32_16x16x32_bf16(fAh[rt][0], bh0, c, 0, 0, 0);
            c = __builtin_amdgcn_mfma_f32_16x16x32_bf16(fAh[rt][0], bl0, c, 0, 0, 0);
            c = __builtin_amdgcn_mfma_f32_16x16x32_bf16(fAl[rt][0], bh0, c, 0, 0, 0);
            c = __builtin_amdgcn_mfma_f32_16x16x32_bf16(fAh[rt][1], bh1, c, 0, 0, 0);
            c = __builtin_amdgcn_mfma_f32_16x16x32_bf16(fAh[rt][1], bl1, c, 0, 0, 0);
            c = __builtin_amdgcn_mfma_f32_16x16x32_bf16(fAl[rt][1], bh1, c, 0, 0, 0);
            acc[rt][ct] = c;
        }
    }
    __syncthreads();   // all frag reads done; Ks may overwrite tiles

    // ---- epilogue: k-values into Ks (C/D layout: col=lane&15, row=quad*4+reg)
    const float NSCL = -1.0f / 4096.0f;
    #pragma unroll
    for (int rt = 0; rt < 2; ++rt)
        #pragma unroll
        for (int ct = 0; ct < 8; ++ct)
            #pragma unroll
            for (int i = 0; i < 4; ++i) {
                int row = rbase + rt * 16 + quad * 4 + i;
                int col = ct * 16 + mrow;
                float d  = acc[rt][ct][i];
                float s2 = sqA[row] + sqB[col];
                float sqd = s2 - 2.0f * d;
                Ks[row * KSTR + col] = expf(sqd * NSCL);
            }
    __syncthreads();

    // ---- numpy leaf sums (identical chains + shfl tree to the passing rounds)
    float leaf[4];
    #pragma unroll
    for (int j = 0; j < 4; ++j) {
        int ch  = t + 256 * j;
        int row = ch >> 3;
        int tt  = ch & 7;
        float s = Ks[row * KSTR + tt];
        #pragma unroll
        for (int q = 1; q < 16; ++q) s += Ks[row * KSTR + tt + 8 * q];
        float p;
        p = __shfl_xor(s, 1); s = s + p;
        p = __shfl_xor(s, 2); s = s + p;
        p = __shfl_xor(s, 4); s = s + p;
        leaf[j] = s;
    }
    if ((t & 7) == 0) {
        int rbase2 = t >> 3;
        #pragma unroll
        for (int j = 0; j < 4; ++j) {
            int row = rbase2 + 32 * j;
            leafs[((size_t)z * 8192 + arow + row) * 64 + cb] = leaf[j];
        }
    }
}

// Phase B: per row, balanced binary tree over its 64 leaf sums
__global__ void rowsum_kernel(const float* __restrict__ leafs, float* __restrict__ rowsums) {
    int tid = blockIdx.x * 256 + threadIdx.x;
    const float4* p = (const float4*)(leafs + (size_t)tid * 64);
    float v[64];
    #pragma unroll
    for (int i = 0; i < 16; ++i) {
        float4 q = p[i];
        v[4*i+0] = q.x; v[4*i+1] = q.y; v[4*i+2] = q.z; v[4*i+3] = q.w;
    }
    #pragma unroll
    for (int n = 32; n >= 1; n >>= 1)
        #pragma unroll
        for (int i = 0; i < 64; ++i)
            if (i < n) v[i] = v[2*i] + v[2*i+1];
    rowsums[tid] = v[0];
}

// Phase C: per matrix, balanced tree over 8192 row sums; /2^26 exact
__global__ void colsum_kernel(const float* __restrict__ rowsums, float* __restrict__ means) {
    __shared__ float A[8192];
    __shared__ float B[4096];
    const int z = blockIdx.x;
    const int t = threadIdx.x;
    const float* src = rowsums + z * 8192;
    for (int i = t; i < 8192; i += 256) A[i] = src[i];
    __syncthreads();
    float* cur = A;
    float* nxt = B;
    for (int n = 4096; n >= 1; n >>= 1) {
        for (int i = t; i < n; i += 256) nxt[i] = cur[2*i] + cur[2*i+1];
        __syncthreads();
        float* tmp = cur; cur = nxt; nxt = tmp;
    }
    if (t == 0) means[z] = cur[0] * (1.0f / 67108864.0f);
}

// Phase D: fp32 combine in reference expression order
__global__ void combine_kernel(const float* __restrict__ means, float* __restrict__ out) {
    float t1 = means[0] + means[1];
    out[0] = t1 - 2.0f * means[2];
}

extern "C" void kernel_launch(void* const* d_in, const int* in_sizes, int n_in,
                              void* d_out, int out_size, void* d_ws, size_t ws_size,
                              hipStream_t stream) {
    const float* x = (const float*)d_in[0];
    const float* y = (const float*)d_in[1];
    float* leafs   = (float*)d_ws;
    float* rowsums = leafs + LEAF_FLOATS;
    float* means   = rowsums + ROW_FLOATS;

    dim3 grid(NPTS / BT, NPTS / BT, 3);
    mmd_tile_kernel<<<grid, 256, 0, stream>>>(x, y, leafs);
    rowsum_kernel<<<(3 * 8192) / 256, 256, 0, stream>>>(leafs, rowsums);
    colsum_kernel<<<3, 256, 0, stream>>>(rowsums, means);
    combine_kernel<<<1, 1, 0, stream>>>(means, (float*)d_out);
}

// Round 9
// 259.962 us; speedup vs baseline: 1.8924x; 1.0694x over previous
//
#include <hip/hip_runtime.h>
#include <cmath>

#define NPTS 8192
#define DIM 64
#define BT 128
#define RSTR 72          // bf16-element row stride for hi/lo tiles (16B-aligned rows)
#define KSTR 132         // float word stride for Ks rows (2-way max on C-layout writes)

#define LEAF_FLOATS (3 * 8192 * 64)
#define ROW_FLOATS  (3 * 8192)

typedef short bf16x8 __attribute__((ext_vector_type(8)));
typedef float f32x4  __attribute__((ext_vector_type(4)));

__device__ __forceinline__ unsigned short f32_bf16_rne(float f) {
    unsigned u = __float_as_uint(f);
    return (unsigned short)((u + 0x7FFFu + ((u >> 16) & 1u)) >> 16);
}
__device__ __forceinline__ float bf16_f32(unsigned short h) {
    return __uint_as_float(((unsigned)h) << 16);
}

// 512 threads / 8 waves per block: same 128x128 tile, same LDS, 2 blocks/CU
// -> 4 waves/SIMD (2x R8's occupancy). All arithmetic chains identical to R8.
__global__ __launch_bounds__(512, 4) void mmd_tile_kernel(
    const float* __restrict__ x, const float* __restrict__ y,
    float* __restrict__ leafs)
{
    __shared__ __align__(16) unsigned short smem[4 * BT * RSTR];  // 73728 B
    __shared__ float sqA[BT];
    __shared__ float sqB[BT];

    unsigned short* Ah = smem;
    unsigned short* Al = smem + 1 * BT * RSTR;
    unsigned short* Bh = smem + 2 * BT * RSTR;
    unsigned short* Bl = smem + 3 * BT * RSTR;
    float* Ks = (float*)smem;     // [128][KSTR] floats, aliases the bf16 tiles

    const int t = threadIdx.x;
    const int z = blockIdx.z;              // 0: k(x,x), 1: k(y,y), 2: k(x,y)
    const float* Ap = (z == 1) ? y : x;
    const float* Bp = (z == 0) ? x : y;

    const size_t arow = (size_t)blockIdx.y * BT;
    const size_t brow = (size_t)blockIdx.x * BT;
    const int cb = blockIdx.x;

    // ---- stage 128x64 fp32 tiles -> bf16 hi/lo tiles (RNE split, same as R8)
    {
        const float4* Ag = (const float4*)(Ap + arow * DIM);
        const float4* Bg = (const float4*)(Bp + brow * DIM);
        #pragma unroll
        for (int it = 0; it < 4; ++it) {
            int e  = it * 512 + t;     // 0..2047, same element set as R8
            int r  = e >> 4;
            int k4 = e & 15;
            float4 va = Ag[e], vb = Bg[e];
            ushort4 ah, al, bh, bl;
            ah.x = f32_bf16_rne(va.x); al.x = f32_bf16_rne(va.x - bf16_f32(ah.x));
            ah.y = f32_bf16_rne(va.y); al.y = f32_bf16_rne(va.y - bf16_f32(ah.y));
            ah.z = f32_bf16_rne(va.z); al.z = f32_bf16_rne(va.z - bf16_f32(ah.z));
            ah.w = f32_bf16_rne(va.w); al.w = f32_bf16_rne(va.w - bf16_f32(ah.w));
            bh.x = f32_bf16_rne(vb.x); bl.x = f32_bf16_rne(vb.x - bf16_f32(bh.x));
            bh.y = f32_bf16_rne(vb.y); bl.y = f32_bf16_rne(vb.y - bf16_f32(bh.y));
            bh.z = f32_bf16_rne(vb.z); bl.z = f32_bf16_rne(vb.z - bf16_f32(bh.z));
            bh.w = f32_bf16_rne(vb.w); bl.w = f32_bf16_rne(vb.w - bf16_f32(bh.w));
            int o = r * RSTR + k4 * 4;
            *(ushort4*)(Ah + o) = ah;
            *(ushort4*)(Al + o) = al;
            *(ushort4*)(Bh + o) = bh;
            *(ushort4*)(Bl + o) = bl;
        }
    }

    // ---- per-row squared norms from GLOBAL fp32 (identical chain to R8)
    if (t < 256) {
        int rid = t & 127;
        const float4* Rg = (const float4*)((t < BT) ? (Ap + (arow + rid) * DIM)
                                                    : (Bp + (brow + rid) * DIM));
        float s = 0.f;
        #pragma unroll
        for (int k4 = 0; k4 < 16; ++k4) {
            float4 v = Rg[k4];
            s = fmaf(v.x, v.x, s); s = fmaf(v.y, v.y, s);
            s = fmaf(v.z, v.z, s); s = fmaf(v.w, v.w, s);
        }
        if (t < BT) sqA[rid] = s; else sqB[rid] = s;
    }
    __syncthreads();

    // ---- MFMA main: wave wv owns rows [16*wv, 16*wv+16); 8 col-tiles
    const int lane = t & 63;
    const int wv   = t >> 6;          // 0..7
    const int mrow = lane & 15;
    const int quad = lane >> 4;
    const int rbase = wv * 16;

    bf16x8 fAh[2], fAl[2];
    #pragma unroll
    for (int kc = 0; kc < 2; ++kc) {
        const unsigned short* p = Ah + (rbase + mrow) * RSTR + kc * 32 + quad * 8;
        fAh[kc] = *(const bf16x8*)p;
        fAl[kc] = *(const bf16x8*)(p + BT * RSTR);
    }

    f32x4 acc[8];
    #pragma unroll
    for (int ct = 0; ct < 8; ++ct)
        acc[ct] = (f32x4){0.f, 0.f, 0.f, 0.f};

    #pragma unroll
    for (int ct = 0; ct < 8; ++ct) {
        const unsigned short* q = Bh + (ct * 16 + mrow) * RSTR + quad * 8;
        bf16x8 bh0 = *(const bf16x8*)(q);
        bf16x8 bh1 = *(const bf16x8*)(q + 32);
        bf16x8 bl0 = *(const bf16x8*)(q + BT * RSTR);
        bf16x8 bl1 = *(const bf16x8*)(q + BT * RSTR + 32);
        f32x4 c = acc[ct];
        // identical 6-pass order per accumulator as R8
        c = __builtin_amdgcn_mfma_f32_16x16x32_bf16(fAh[0], bh0, c, 0, 0, 0);
        c = __builtin_amdgcn_mfma_f32_16x16x32_bf16(fAh[0], bl0, c, 0, 0, 0);
        c = __builtin_amdgcn_mfma_f32_16x16x32_bf16(fAl[0], bh0, c, 0, 0, 0);
        c = __builtin_amdgcn_mfma_f32_16x16x32_bf16(fAh[1], bh1, c, 0, 0, 0);
        c = __builtin_amdgcn_mfma_f32_16x16x32_bf16(fAh[1], bl1, c, 0, 0, 0);
        c = __builtin_amdgcn_mfma_f32_16x16x32_bf16(fAl[1], bh1, c, 0, 0, 0);
        acc[ct] = c;
    }
    __syncthreads();   // all frag reads done; Ks may overwrite tiles

    // ---- epilogue: k-values into Ks (C/D layout: col=lane&15, row=quad*4+reg)
    const float NSCL = -1.0f / 4096.0f;
    #pragma unroll
    for (int ct = 0; ct < 8; ++ct)
        #pragma unroll
        for (int i = 0; i < 4; ++i) {
            int row = rbase + quad * 4 + i;
            int col = ct * 16 + mrow;
            float d  = acc[ct][i];
            float s2 = sqA[row] + sqB[col];
            float sqd = s2 - 2.0f * d;
            Ks[row * KSTR + col] = expf(sqd * NSCL);
        }
    __syncthreads();

    // ---- numpy leaf sums (identical chains + shfl tree to R8)
    float leaf[2];
    #pragma unroll
    for (int j = 0; j < 2; ++j) {
        int ch  = t + 512 * j;        // chain id 0..1023
        int row = ch >> 3;
        int tt  = ch & 7;
        float s = Ks[row * KSTR + tt];
        #pragma unroll
        for (int q = 1; q < 16; ++q) s += Ks[row * KSTR + tt + 8 * q];
        float p;
        p = __shfl_xor(s, 1); s = s + p;
        p = __shfl_xor(s, 2); s = s + p;
        p = __shfl_xor(s, 4); s = s + p;
        leaf[j] = s;
    }
    if ((t & 7) == 0) {
        int rb = t >> 3;              // 0..63
        #pragma unroll
        for (int j = 0; j < 2; ++j) {
            int row = rb + 64 * j;
            leafs[((size_t)z * 8192 + arow + row) * 64 + cb] = leaf[j];
        }
    }
}

// Phase B: per row, balanced binary tree over its 64 leaf sums
__global__ void rowsum_kernel(const float* __restrict__ leafs, float* __restrict__ rowsums) {
    int tid = blockIdx.x * 256 + threadIdx.x;
    const float4* p = (const float4*)(leafs + (size_t)tid * 64);
    float v[64];
    #pragma unroll
    for (int i = 0; i < 16; ++i) {
        float4 q = p[i];
        v[4*i+0] = q.x; v[4*i+1] = q.y; v[4*i+2] = q.z; v[4*i+3] = q.w;
    }
    #pragma unroll
    for (int n = 32; n >= 1; n >>= 1)
        #pragma unroll
        for (int i = 0; i < 64; ++i)
            if (i < n) v[i] = v[2*i] + v[2*i+1];
    rowsums[tid] = v[0];
}

// Phase C: per matrix, balanced tree over 8192 row sums; /2^26 exact
__global__ void colsum_kernel(const float* __restrict__ rowsums, float* __restrict__ means) {
    __shared__ float A[8192];
    __shared__ float B[4096];
    const int z = blockIdx.x;
    const int t = threadIdx.x;
    const float* src = rowsums + z * 8192;
    for (int i = t; i < 8192; i += 256) A[i] = src[i];
    __syncthreads();
    float* cur = A;
    float* nxt = B;
    for (int n = 4096; n >= 1; n >>= 1) {
        for (int i = t; i < n; i += 256) nxt[i] = cur[2*i] + cur[2*i+1];
        __syncthreads();
        float* tmp = cur; cur = nxt; nxt = tmp;
    }
    if (t == 0) means[z] = cur[0] * (1.0f / 67108864.0f);
}

// Phase D: fp32 combine in reference expression order
__global__ void combine_kernel(const float* __restrict__ means, float* __restrict__ out) {
    float t1 = means[0] + means[1];
    out[0] = t1 - 2.0f * means[2];
}

extern "C" void kernel_launch(void* const* d_in, const int* in_sizes, int n_in,
                              void* d_out, int out_size, void* d_ws, size_t ws_size,
                              hipStream_t stream) {
    const float* x = (const float*)d_in[0];
    const float* y = (const float*)d_in[1];
    float* leafs   = (float*)d_ws;
    float* rowsums = leafs + LEAF_FLOATS;
    float* means   = rowsums + ROW_FLOATS;

    dim3 grid(NPTS / BT, NPTS / BT, 3);
    mmd_tile_kernel<<<grid, 512, 0, stream>>>(x, y, leafs);
    rowsum_kernel<<<(3 * 8192) / 256, 256, 0, stream>>>(leafs, rowsums);
    colsum_kernel<<<3, 256, 0, stream>>>(rowsums, means);
    combine_kernel<<<1, 1, 0, stream>>>(means, (float*)d_out);
}

// Round 10
// 215.405 us; speedup vs baseline: 2.2838x; 1.2069x over previous
//
#include <hip/hip_runtime.h>
#include <cmath>

#define NPTS 8192
#define DIM 64
#define BT 128
#define RSTR 72          // bf16-element row stride for hi/lo LDS tiles (144B rows)
#define KSTR 132         // float word stride for Ks rows

// ws layout (float offsets)
#define LEAF_F   0
#define LEAF_N   (3 * 8192 * 64)          // 1572864
#define ROWS_F   (LEAF_F + LEAF_N)
#define ROWS_N   (3 * 8192)
#define MEANS_F  (ROWS_F + ROWS_N)
#define NX_F     ((MEANS_F + 3 + 3) & ~3) // 16B-align
#define NY_F     (NX_F + 8192)
#define SPLIT_F  (NY_F + 8192)            // ushort arrays start here (16B-aligned)
#define SPLIT_ELEMS (NPTS * DIM)          // 524288 ushorts per array

typedef short bf16x8 __attribute__((ext_vector_type(8)));
typedef float f32x4  __attribute__((ext_vector_type(4)));
typedef unsigned short ushort8v __attribute__((ext_vector_type(8)));

__device__ __forceinline__ unsigned short f32_bf16_rne(float f) {
    unsigned u = __float_as_uint(f);
    return (unsigned short)((u + 0x7FFFu + ((u >> 16) & 1u)) >> 16);
}
__device__ __forceinline__ float bf16_f32(unsigned short h) {
    return __uint_as_float(((unsigned)h) << 16);
}

// ---- prep 1: bf16 hi/lo RNE split of both inputs (identical chain to R9)
__global__ void presplit_kernel(const float4* __restrict__ xv, const float4* __restrict__ yv,
                                ushort4* __restrict__ Xh, ushort4* __restrict__ Xl,
                                ushort4* __restrict__ Yh, ushort4* __restrict__ Yl) {
    int i = blockIdx.x * 256 + threadIdx.x;   // 0..131071
    float4 v = xv[i];
    ushort4 h, l;
    h.x = f32_bf16_rne(v.x); l.x = f32_bf16_rne(v.x - bf16_f32(h.x));
    h.y = f32_bf16_rne(v.y); l.y = f32_bf16_rne(v.y - bf16_f32(h.y));
    h.z = f32_bf16_rne(v.z); l.z = f32_bf16_rne(v.z - bf16_f32(h.z));
    h.w = f32_bf16_rne(v.w); l.w = f32_bf16_rne(v.w - bf16_f32(h.w));
    Xh[i] = h; Xl[i] = l;
    v = yv[i];
    h.x = f32_bf16_rne(v.x); l.x = f32_bf16_rne(v.x - bf16_f32(h.x));
    h.y = f32_bf16_rne(v.y); l.y = f32_bf16_rne(v.y - bf16_f32(h.y));
    h.z = f32_bf16_rne(v.z); l.z = f32_bf16_rne(v.z - bf16_f32(h.z));
    h.w = f32_bf16_rne(v.w); l.w = f32_bf16_rne(v.w - bf16_f32(h.w));
    Yh[i] = h; Yl[i] = l;
}

// ---- prep 2: per-row squared norms (identical float4 k-ascending fma chain)
__global__ void norms_kernel(const float* __restrict__ x, const float* __restrict__ y,
                             float* __restrict__ nx, float* __restrict__ ny) {
    int r = blockIdx.x * 256 + threadIdx.x;   // 0..16383
    const float* src = (r < NPTS) ? (x + (size_t)r * DIM) : (y + (size_t)(r - NPTS) * DIM);
    const float4* Rg = (const float4*)src;
    float s = 0.f;
    #pragma unroll
    for (int k4 = 0; k4 < 16; ++k4) {
        float4 v = Rg[k4];
        s = fmaf(v.x, v.x, s); s = fmaf(v.y, v.y, s);
        s = fmaf(v.z, v.z, s); s = fmaf(v.w, v.w, s);
    }
    if (r < NPTS) nx[r] = s; else ny[r - NPTS] = s;
}

// ---- main tile kernel: pure-copy staging, 32x64 wave tiles, bit-exact chains
__global__ __launch_bounds__(512, 4) void mmd_tile_kernel(
    const unsigned short* __restrict__ Xh, const unsigned short* __restrict__ Xl,
    const unsigned short* __restrict__ Yh, const unsigned short* __restrict__ Yl,
    const float* __restrict__ nx, const float* __restrict__ ny,
    float* __restrict__ leafs)
{
    __shared__ __align__(16) unsigned short smem[4 * BT * RSTR];  // 73728 B
    __shared__ float sqA[BT];
    __shared__ float sqB[BT];

    unsigned short* Ah = smem;
    unsigned short* Al = smem + 1 * BT * RSTR;
    unsigned short* Bh = smem + 2 * BT * RSTR;
    unsigned short* Bl = smem + 3 * BT * RSTR;
    float* Ks = (float*)smem;     // [128][KSTR] floats, aliases the bf16 tiles

    const int t = threadIdx.x;
    const int z = blockIdx.z;              // 0: k(x,x), 1: k(y,y), 2: k(x,y)
    const size_t arow = (size_t)blockIdx.y * BT;
    const size_t brow = (size_t)blockIdx.x * BT;
    const int cb = blockIdx.x;

    const unsigned short* gAh = ((z == 1) ? Yh : Xh) + arow * DIM;
    const unsigned short* gAl = ((z == 1) ? Yl : Xl) + arow * DIM;
    const unsigned short* gBh = ((z == 0) ? Xh : Yh) + brow * DIM;
    const unsigned short* gBl = ((z == 0) ? Xl : Yl) + brow * DIM;

    // ---- staging: pure ushort8 copy, 8 chunks/thread (4 arrays x 2 halves)
    {
        const unsigned short* gs[4] = {gAh, gAl, gBh, gBl};
        unsigned short* ld[4] = {Ah, Al, Bh, Bl};
        #pragma unroll
        for (int a = 0; a < 4; ++a)
            #pragma unroll
            for (int half = 0; half < 2; ++half) {
                int idx = half * 512 + t;        // 0..1023
                int r   = idx >> 3;
                int k8  = idx & 7;
                *(ushort8v*)(ld[a] + r * RSTR + k8 * 8) =
                    *(const ushort8v*)(gs[a] + r * DIM + k8 * 8);
            }
    }

    // ---- norms: load precomputed (identical values to R9's in-kernel chains)
    if (t < 256) {
        const float* nA = (z == 1) ? ny : nx;
        const float* nB = (z == 0) ? nx : ny;
        if (t < BT) sqA[t] = nA[arow + t];
        else        sqB[t - BT] = nB[brow + t - BT];
    }
    __syncthreads();

    // ---- MFMA main: wave -> 32x64 sub-tile (2 row-tiles x 4 col-tiles)
    const int lane = t & 63;
    const int wv   = t >> 6;               // 0..7
    const int mrow = lane & 15;
    const int quad = lane >> 4;
    const int rblk = (wv & 3) << 5;        // 0,32,64,96
    const int cblk = (wv >> 2) << 6;       // 0,64

    bf16x8 fAh[2][2], fAl[2][2];
    #pragma unroll
    for (int rt = 0; rt < 2; ++rt)
        #pragma unroll
        for (int kc = 0; kc < 2; ++kc) {
            const unsigned short* p = Ah + (rblk + rt * 16 + mrow) * RSTR + kc * 32 + quad * 8;
            fAh[rt][kc] = *(const bf16x8*)p;
            fAl[rt][kc] = *(const bf16x8*)(p + BT * RSTR);
        }

    f32x4 acc[2][4];
    #pragma unroll
    for (int rt = 0; rt < 2; ++rt)
        #pragma unroll
        for (int ct = 0; ct < 4; ++ct)
            acc[rt][ct] = (f32x4){0.f, 0.f, 0.f, 0.f};

    #pragma unroll
    for (int ct = 0; ct < 4; ++ct) {
        const unsigned short* q = Bh + (cblk + ct * 16 + mrow) * RSTR + quad * 8;
        bf16x8 bh0 = *(const bf16x8*)(q);
        bf16x8 bh1 = *(const bf16x8*)(q + 32);
        bf16x8 bl0 = *(const bf16x8*)(q + BT * RSTR);
        bf16x8 bl1 = *(const bf16x8*)(q + BT * RSTR + 32);
        #pragma unroll
        for (int rt = 0; rt < 2; ++rt) {
            f32x4 c = acc[rt][ct];
            // identical 6-pass order per accumulator as R8/R9
            c = __builtin_amdgcn_mfma_f32_16x16x32_bf16(fAh[rt][0], bh0, c, 0, 0, 0);
            c = __builtin_amdgcn_mfma_f32_16x16x32_bf16(fAh[rt][0], bl0, c, 0, 0, 0);
            c = __builtin_amdgcn_mfma_f32_16x16x32_bf16(fAl[rt][0], bh0, c, 0, 0, 0);
            c = __builtin_amdgcn_mfma_f32_16x16x32_bf16(fAh[rt][1], bh1, c, 0, 0, 0);
            c = __builtin_amdgcn_mfma_f32_16x16x32_bf16(fAh[rt][1], bl1, c, 0, 0, 0);
            c = __builtin_amdgcn_mfma_f32_16x16x32_bf16(fAl[rt][1], bh1, c, 0, 0, 0);
            acc[rt][ct] = c;
        }
    }
    __syncthreads();   // all frag reads done; Ks may overwrite tiles

    // ---- epilogue: k-values into Ks (C/D layout: col=lane&15, row=quad*4+reg)
    const float NSCL = -1.0f / 4096.0f;
    #pragma unroll
    for (int rt = 0; rt < 2; ++rt)
        #pragma unroll
        for (int ct = 0; ct < 4; ++ct)
            #pragma unroll
            for (int i = 0; i < 4; ++i) {
                int row = rblk + rt * 16 + quad * 4 + i;
                int col = cblk + ct * 16 + mrow;
                float d  = acc[rt][ct][i];
                float s2 = sqA[row] + sqB[col];
                float sqd = s2 - 2.0f * d;
                Ks[row * KSTR + col] = expf(sqd * NSCL);
            }
    __syncthreads();

    // ---- numpy leaf sums (identical chains + shfl tree to R8/R9)
    float leaf[2];
    #pragma unroll
    for (int j = 0; j < 2; ++j) {
        int ch  = t + 512 * j;        // chain id 0..1023
        int row = ch >> 3;
        int tt  = ch & 7;
        float s = Ks[row * KSTR + tt];
        #pragma unroll
        for (int q = 1; q < 16; ++q) s += Ks[row * KSTR + tt + 8 * q];
        float p;
        p = __shfl_xor(s, 1); s = s + p;
        p = __shfl_xor(s, 2); s = s + p;
        p = __shfl_xor(s, 4); s = s + p;
        leaf[j] = s;
    }
    if ((t & 7) == 0) {
        int rb = t >> 3;              // 0..63
        #pragma unroll
        for (int j = 0; j < 2; ++j) {
            int row = rb + 64 * j;
            leafs[((size_t)z * 8192 + arow + row) * 64 + cb] = leaf[j];
        }
    }
}

// Phase B: per row, balanced binary tree over its 64 leaf sums
__global__ void rowsum_kernel(const float* __restrict__ leafs, float* __restrict__ rowsums) {
    int tid = blockIdx.x * 256 + threadIdx.x;
    const float4* p = (const float4*)(leafs + (size_t)tid * 64);
    float v[64];
    #pragma unroll
    for (int i = 0; i < 16; ++i) {
        float4 q = p[i];
        v[4*i+0] = q.x; v[4*i+1] = q.y; v[4*i+2] = q.z; v[4*i+3] = q.w;
    }
    #pragma unroll
    for (int n = 32; n >= 1; n >>= 1)
        #pragma unroll
        for (int i = 0; i < 64; ++i)
            if (i < n) v[i] = v[2*i] + v[2*i+1];
    rowsums[tid] = v[0];
}

// Phase C: per matrix, balanced tree over 8192 row sums; /2^26 exact
__global__ void colsum_kernel(const float* __restrict__ rowsums, float* __restrict__ means) {
    __shared__ float A[8192];
    __shared__ float B[4096];
    const int z = blockIdx.x;
    const int t = threadIdx.x;
    const float* src = rowsums + z * 8192;
    for (int i = t; i < 8192; i += 256) A[i] = src[i];
    __syncthreads();
    float* cur = A;
    float* nxt = B;
    for (int n = 4096; n >= 1; n >>= 1) {
        for (int i = t; i < n; i += 256) nxt[i] = cur[2*i] + cur[2*i+1];
        __syncthreads();
        float* tmp = cur; cur = nxt; nxt = tmp;
    }
    if (t == 0) means[z] = cur[0] * (1.0f / 67108864.0f);
}

// Phase D: fp32 combine in reference expression order
__global__ void combine_kernel(const float* __restrict__ means, float* __restrict__ out) {
    float t1 = means[0] + means[1];
    out[0] = t1 - 2.0f * means[2];
}

extern "C" void kernel_launch(void* const* d_in, const int* in_sizes, int n_in,
                              void* d_out, int out_size, void* d_ws, size_t ws_size,
                              hipStream_t stream) {
    const float* x = (const float*)d_in[0];
    const float* y = (const float*)d_in[1];
    float* wsf     = (float*)d_ws;
    float* leafs   = wsf + LEAF_F;
    float* rowsums = wsf + ROWS_F;
    float* means   = wsf + MEANS_F;
    float* nx      = wsf + NX_F;
    float* ny      = wsf + NY_F;
    unsigned short* Xh = (unsigned short*)(wsf + SPLIT_F);
    unsigned short* Xl = Xh + SPLIT_ELEMS;
    unsigned short* Yh = Xl + SPLIT_ELEMS;
    unsigned short* Yl = Yh + SPLIT_ELEMS;

    presplit_kernel<<<512, 256, 0, stream>>>((const float4*)x, (const float4*)y,
                                             (ushort4*)Xh, (ushort4*)Xl,
                                             (ushort4*)Yh, (ushort4*)Yl);
    norms_kernel<<<64, 256, 0, stream>>>(x, y, nx, ny);
    dim3 grid(NPTS / BT, NPTS / BT, 3);
    mmd_tile_kernel<<<grid, 512, 0, stream>>>(Xh, Xl, Yh, Yl, nx, ny, leafs);
    rowsum_kernel<<<(3 * 8192) / 256, 256, 0, stream>>>(leafs, rowsums);
    colsum_kernel<<<3, 256, 0, stream>>>(rowsums, means);
    combine_kernel<<<1, 1, 0, stream>>>(means, (float*)d_out);
}

// Round 11
// 200.560 us; speedup vs baseline: 2.4529x; 1.0740x over previous
//
#include <hip/hip_runtime.h>
#include <cmath>

#define NPTS 8192
#define DIM 64
#define BT 128
#define RSTR 72          // bf16-element row stride for hi/lo LDS tiles (144B rows)
#define KSTR 132         // float word stride for Ks rows

// ws layout (float offsets)
#define LEAF_F   0
#define LEAF_N   (3 * 8192 * 64)          // 1572864
#define ROWS_F   (LEAF_F + LEAF_N)
#define ROWS_N   (3 * 8192)
#define MEANS_F  (ROWS_F + ROWS_N)
#define NX_F     ((MEANS_F + 3 + 3) & ~3) // 16B-align
#define NY_F     (NX_F + 8192)
#define SPLIT_F  (NY_F + 8192)            // ushort arrays start here (16B-aligned)
#define SPLIT_ELEMS (NPTS * DIM)          // 524288 ushorts per array

typedef short bf16x8 __attribute__((ext_vector_type(8)));
typedef float f32x4  __attribute__((ext_vector_type(4)));
typedef unsigned short ushort8v __attribute__((ext_vector_type(8)));

__device__ __forceinline__ unsigned short f32_bf16_rne(float f) {
    unsigned u = __float_as_uint(f);
    return (unsigned short)((u + 0x7FFFu + ((u >> 16) & 1u)) >> 16);
}
__device__ __forceinline__ float bf16_f32(unsigned short h) {
    return __uint_as_float(((unsigned)h) << 16);
}

// ---- prep 1: bf16 hi/lo RNE split of both inputs (identical chain to R10)
__global__ void presplit_kernel(const float4* __restrict__ xv, const float4* __restrict__ yv,
                                ushort4* __restrict__ Xh, ushort4* __restrict__ Xl,
                                ushort4* __restrict__ Yh, ushort4* __restrict__ Yl) {
    int i = blockIdx.x * 256 + threadIdx.x;   // 0..131071
    float4 v = xv[i];
    ushort4 h, l;
    h.x = f32_bf16_rne(v.x); l.x = f32_bf16_rne(v.x - bf16_f32(h.x));
    h.y = f32_bf16_rne(v.y); l.y = f32_bf16_rne(v.y - bf16_f32(h.y));
    h.z = f32_bf16_rne(v.z); l.z = f32_bf16_rne(v.z - bf16_f32(h.z));
    h.w = f32_bf16_rne(v.w); l.w = f32_bf16_rne(v.w - bf16_f32(h.w));
    Xh[i] = h; Xl[i] = l;
    v = yv[i];
    h.x = f32_bf16_rne(v.x); l.x = f32_bf16_rne(v.x - bf16_f32(h.x));
    h.y = f32_bf16_rne(v.y); l.y = f32_bf16_rne(v.y - bf16_f32(h.y));
    h.z = f32_bf16_rne(v.z); l.z = f32_bf16_rne(v.z - bf16_f32(h.z));
    h.w = f32_bf16_rne(v.w); l.w = f32_bf16_rne(v.w - bf16_f32(h.w));
    Yh[i] = h; Yl[i] = l;
}

// ---- prep 2: per-row squared norms (identical float4 k-ascending fma chain)
__global__ void norms_kernel(const float* __restrict__ x, const float* __restrict__ y,
                             float* __restrict__ nx, float* __restrict__ ny) {
    int r = blockIdx.x * 256 + threadIdx.x;   // 0..16383
    const float* src = (r < NPTS) ? (x + (size_t)r * DIM) : (y + (size_t)(r - NPTS) * DIM);
    const float4* Rg = (const float4*)src;
    float s = 0.f;
    #pragma unroll
    for (int k4 = 0; k4 < 16; ++k4) {
        float4 v = Rg[k4];
        s = fmaf(v.x, v.x, s); s = fmaf(v.y, v.y, s);
        s = fmaf(v.z, v.z, s); s = fmaf(v.w, v.w, s);
    }
    if (r < NPTS) nx[r] = s; else ny[r - NPTS] = s;
}

// ---- main tile kernel. For z<2 (symmetric xx/yy) only tiles bx>=by run;
//      off-diagonal tiles also emit the mirror tile's leaf sums as COLUMN
//      chains over the same Ks tile (numpy's kernel matrix is bitwise
//      symmetric, so mirror values are identical).
__global__ __launch_bounds__(512, 4) void mmd_tile_kernel(
    const unsigned short* __restrict__ Xh, const unsigned short* __restrict__ Xl,
    const unsigned short* __restrict__ Yh, const unsigned short* __restrict__ Yl,
    const float* __restrict__ nx, const float* __restrict__ ny,
    float* __restrict__ leafs)
{
    const int z  = blockIdx.z;             // 0: k(x,x), 1: k(y,y), 2: k(x,y)
    const int bx = blockIdx.x;             // col-block
    const int by = blockIdx.y;             // row-block
    if (z < 2 && bx < by) return;          // lower triangle mirrored from upper

    __shared__ __align__(16) unsigned short smem[4 * BT * RSTR];  // 73728 B
    __shared__ float sqA[BT];
    __shared__ float sqB[BT];

    unsigned short* Ah = smem;
    unsigned short* Al = smem + 1 * BT * RSTR;
    unsigned short* Bh = smem + 2 * BT * RSTR;
    unsigned short* Bl = smem + 3 * BT * RSTR;
    float* Ks = (float*)smem;     // [128][KSTR] floats, aliases the bf16 tiles

    const int t = threadIdx.x;
    const size_t arow = (size_t)by * BT;
    const size_t brow = (size_t)bx * BT;
    const int cb = bx;

    const unsigned short* gAh = ((z == 1) ? Yh : Xh) + arow * DIM;
    const unsigned short* gAl = ((z == 1) ? Yl : Xl) + arow * DIM;
    const unsigned short* gBh = ((z == 0) ? Xh : Yh) + brow * DIM;
    const unsigned short* gBl = ((z == 0) ? Xl : Yl) + brow * DIM;

    // ---- staging: pure ushort8 copy, 8 chunks/thread
    {
        const unsigned short* gs[4] = {gAh, gAl, gBh, gBl};
        unsigned short* ld[4] = {Ah, Al, Bh, Bl};
        #pragma unroll
        for (int a = 0; a < 4; ++a)
            #pragma unroll
            for (int half = 0; half < 2; ++half) {
                int idx = half * 512 + t;        // 0..1023
                int r   = idx >> 3;
                int k8  = idx & 7;
                *(ushort8v*)(ld[a] + r * RSTR + k8 * 8) =
                    *(const ushort8v*)(gs[a] + r * DIM + k8 * 8);
            }
    }

    // ---- norms: load precomputed
    if (t < 256) {
        const float* nA = (z == 1) ? ny : nx;
        const float* nB = (z == 0) ? nx : ny;
        if (t < BT) sqA[t] = nA[arow + t];
        else        sqB[t - BT] = nB[brow + t - BT];
    }
    __syncthreads();

    // ---- MFMA main: wave -> 32x64 sub-tile (2 row-tiles x 4 col-tiles)
    const int lane = t & 63;
    const int wv   = t >> 6;               // 0..7
    const int mrow = lane & 15;
    const int quad = lane >> 4;
    const int rblk = (wv & 3) << 5;        // 0,32,64,96
    const int cblk = (wv >> 2) << 6;       // 0,64

    bf16x8 fAh[2][2], fAl[2][2];
    #pragma unroll
    for (int rt = 0; rt < 2; ++rt)
        #pragma unroll
        for (int kc = 0; kc < 2; ++kc) {
            const unsigned short* p = Ah + (rblk + rt * 16 + mrow) * RSTR + kc * 32 + quad * 8;
            fAh[rt][kc] = *(const bf16x8*)p;
            fAl[rt][kc] = *(const bf16x8*)(p + BT * RSTR);
        }

    f32x4 acc[2][4];
    #pragma unroll
    for (int rt = 0; rt < 2; ++rt)
        #pragma unroll
        for (int ct = 0; ct < 4; ++ct)
            acc[rt][ct] = (f32x4){0.f, 0.f, 0.f, 0.f};

    #pragma unroll
    for (int ct = 0; ct < 4; ++ct) {
        const unsigned short* q = Bh + (cblk + ct * 16 + mrow) * RSTR + quad * 8;
        bf16x8 bh0 = *(const bf16x8*)(q);
        bf16x8 bh1 = *(const bf16x8*)(q + 32);
        bf16x8 bl0 = *(const bf16x8*)(q + BT * RSTR);
        bf16x8 bl1 = *(const bf16x8*)(q + BT * RSTR + 32);
        #pragma unroll
        for (int rt = 0; rt < 2; ++rt) {
            f32x4 c = acc[rt][ct];
            // identical 6-pass order per accumulator as R8-R10
            c = __builtin_amdgcn_mfma_f32_16x16x32_bf16(fAh[rt][0], bh0, c, 0, 0, 0);
            c = __builtin_amdgcn_mfma_f32_16x16x32_bf16(fAh[rt][0], bl0, c, 0, 0, 0);
            c = __builtin_amdgcn_mfma_f32_16x16x32_bf16(fAl[rt][0], bh0, c, 0, 0, 0);
            c = __builtin_amdgcn_mfma_f32_16x16x32_bf16(fAh[rt][1], bh1, c, 0, 0, 0);
            c = __builtin_amdgcn_mfma_f32_16x16x32_bf16(fAh[rt][1], bl1, c, 0, 0, 0);
            c = __builtin_amdgcn_mfma_f32_16x16x32_bf16(fAl[rt][1], bh1, c, 0, 0, 0);
            acc[rt][ct] = c;
        }
    }
    __syncthreads();   // all frag reads done; Ks may overwrite tiles

    // ---- epilogue: k-values into Ks (C/D layout: col=lane&15, row=quad*4+reg)
    const float NSCL = -1.0f / 4096.0f;
    #pragma unroll
    for (int rt = 0; rt < 2; ++rt)
        #pragma unroll
        for (int ct = 0; ct < 4; ++ct)
            #pragma unroll
            for (int i = 0; i < 4; ++i) {
                int row = rblk + rt * 16 + quad * 4 + i;
                int col = cblk + ct * 16 + mrow;
                float d  = acc[rt][ct][i];
                float s2 = sqA[row] + sqB[col];
                float sqd = s2 - 2.0f * d;
                Ks[row * KSTR + col] = expf(sqd * NSCL);
            }
    __syncthreads();

    // ---- numpy leaf sums, row chains (identical to R10)
    float leaf[2];
    #pragma unroll
    for (int j = 0; j < 2; ++j) {
        int ch  = t + 512 * j;        // chain id 0..1023
        int row = ch >> 3;
        int tt  = ch & 7;
        float s = Ks[row * KSTR + tt];
        #pragma unroll
        for (int q = 1; q < 16; ++q) s += Ks[row * KSTR + tt + 8 * q];
        float p;
        p = __shfl_xor(s, 1); s = s + p;
        p = __shfl_xor(s, 2); s = s + p;
        p = __shfl_xor(s, 4); s = s + p;
        leaf[j] = s;
    }
    if ((t & 7) == 0) {
        int rb = t >> 3;              // 0..63
        #pragma unroll
        for (int j = 0; j < 2; ++j) {
            int row = rb + 64 * j;
            leafs[((size_t)z * 8192 + arow + row) * 64 + cb] = leaf[j];
        }
    }

    // ---- mirror tile's leaf sums (only z<2, strict off-diagonal): the
    //      mirror tile's row c equals our COLUMN c; same chain structure.
    if (z < 2 && bx > by) {
        float mleaf[2];
        #pragma unroll
        for (int j = 0; j < 2; ++j) {
            int ch  = t + 512 * j;    // chain id 0..1023
            int c   = ch >> 3;        // mirror-row = our column
            int tt  = ch & 7;
            float s = Ks[tt * KSTR + c];
            #pragma unroll
            for (int q = 1; q < 16; ++q) s += Ks[(tt + 8 * q) * KSTR + c];
            float p;
            p = __shfl_xor(s, 1); s = s + p;
            p = __shfl_xor(s, 2); s = s + p;
            p = __shfl_xor(s, 4); s = s + p;
            mleaf[j] = s;
        }
        if ((t & 7) == 0) {
            int rb = t >> 3;          // 0..63
            #pragma unroll
            for (int j = 0; j < 2; ++j) {
                int row = rb + 64 * j;            // mirror-row within tile
                leafs[((size_t)z * 8192 + brow + row) * 64 + by] = mleaf[j];
            }
        }
    }
}

// Phase B: per row, balanced binary tree over its 64 leaf sums
__global__ void rowsum_kernel(const float* __restrict__ leafs, float* __restrict__ rowsums) {
    int tid = blockIdx.x * 256 + threadIdx.x;
    const float4* p = (const float4*)(leafs + (size_t)tid * 64);
    float v[64];
    #pragma unroll
    for (int i = 0; i < 16; ++i) {
        float4 q = p[i];
        v[4*i+0] = q.x; v[4*i+1] = q.y; v[4*i+2] = q.z; v[4*i+3] = q.w;
    }
    #pragma unroll
    for (int n = 32; n >= 1; n >>= 1)
        #pragma unroll
        for (int i = 0; i < 64; ++i)
            if (i < n) v[i] = v[2*i] + v[2*i+1];
    rowsums[tid] = v[0];
}

// Phase C: per matrix, balanced tree over 8192 row sums; /2^26 exact
__global__ void colsum_kernel(const float* __restrict__ rowsums, float* __restrict__ means) {
    __shared__ float A[8192];
    __shared__ float B[4096];
    const int z = blockIdx.x;
    const int t = threadIdx.x;
    const float* src = rowsums + z * 8192;
    for (int i = t; i < 8192; i += 256) A[i] = src[i];
    __syncthreads();
    float* cur = A;
    float* nxt = B;
    for (int n = 4096; n >= 1; n >>= 1) {
        for (int i = t; i < n; i += 256) nxt[i] = cur[2*i] + cur[2*i+1];
        __syncthreads();
        float* tmp = cur; cur = nxt; nxt = tmp;
    }
    if (t == 0) means[z] = cur[0] * (1.0f / 67108864.0f);
}

// Phase D: fp32 combine in reference expression order
__global__ void combine_kernel(const float* __restrict__ means, float* __restrict__ out) {
    float t1 = means[0] + means[1];
    out[0] = t1 - 2.0f * means[2];
}

extern "C" void kernel_launch(void* const* d_in, const int* in_sizes, int n_in,
                              void* d_out, int out_size, void* d_ws, size_t ws_size,
                              hipStream_t stream) {
    const float* x = (const float*)d_in[0];
    const float* y = (const float*)d_in[1];
    float* wsf     = (float*)d_ws;
    float* leafs   = wsf + LEAF_F;
    float* rowsums = wsf + ROWS_F;
    float* means   = wsf + MEANS_F;
    float* nx      = wsf + NX_F;
    float* ny      = wsf + NY_F;
    unsigned short* Xh = (unsigned short*)(wsf + SPLIT_F);
    unsigned short* Xl = Xh + SPLIT_ELEMS;
    unsigned short* Yh = Xl + SPLIT_ELEMS;
    unsigned short* Yl = Yh + SPLIT_ELEMS;

    presplit_kernel<<<512, 256, 0, stream>>>((const float4*)x, (const float4*)y,
                                             (ushort4*)Xh, (ushort4*)Xl,
                                             (ushort4*)Yh, (ushort4*)Yl);
    norms_kernel<<<64, 256, 0, stream>>>(x, y, nx, ny);
    dim3 grid(NPTS / BT, NPTS / BT, 3);
    mmd_tile_kernel<<<grid, 512, 0, stream>>>(Xh, Xl, Yh, Yl, nx, ny, leafs);
    rowsum_kernel<<<(3 * 8192) / 256, 256, 0, stream>>>(leafs, rowsums);
    colsum_kernel<<<3, 256, 0, stream>>>(rowsums, means);
    combine_kernel<<<1, 1, 0, stream>>>(means, (float*)d_out);
}

// Round 12
// 171.757 us; speedup vs baseline: 2.8642x; 1.1677x over previous
//
#include <hip/hip_runtime.h>
#include <cmath>

#define NPTS 8192
#define DIM 64
#define BT 128
#define RSTR 72          // bf16-element row stride for hi/lo LDS tiles (144B rows)
#define KSTR 132         // float word stride for Ks rows

// ws layout (float offsets)
#define LEAF_F   0
#define LEAF_N   (3 * 8192 * 64)          // 1572864
#define ROWS_F   (LEAF_F + LEAF_N)
#define ROWS_N   (3 * 8192)
#define MEANS_F  (ROWS_F + ROWS_N)
#define NX_F     ((MEANS_F + 3 + 3) & ~3) // 16B-align
#define NY_F     (NX_F + 8192)
#define SPLIT_F  (NY_F + 8192)            // ushort arrays start here (16B-aligned)
#define SPLIT_ELEMS (NPTS * DIM)          // 524288 ushorts per array

typedef short bf16x8 __attribute__((ext_vector_type(8)));
typedef float f32x4  __attribute__((ext_vector_type(4)));
typedef unsigned short ushort8v __attribute__((ext_vector_type(8)));

__device__ __forceinline__ unsigned short f32_bf16_rne(float f) {
    unsigned u = __float_as_uint(f);
    return (unsigned short)((u + 0x7FFFu + ((u >> 16) & 1u)) >> 16);
}
__device__ __forceinline__ float bf16_f32(unsigned short h) {
    return __uint_as_float(((unsigned)h) << 16);
}

// ---- fused prep: bf16 hi/lo RNE split + row norms (identical chains to R11;
//      interleaving split ops does not alter the norm fma chain)
__global__ void prep_kernel(const float* __restrict__ x, const float* __restrict__ y,
                            ushort4* __restrict__ Xh, ushort4* __restrict__ Xl,
                            ushort4* __restrict__ Yh, ushort4* __restrict__ Yl,
                            float* __restrict__ nx, float* __restrict__ ny) {
    int r = blockIdx.x * 256 + threadIdx.x;   // 0..16383
    int isY = r >= NPTS;
    int rr = isY ? r - NPTS : r;
    const float4* Rg = (const float4*)((isY ? y : x) + (size_t)rr * DIM);
    ushort4* Hh = (isY ? Yh : Xh) + rr * 16;
    ushort4* Hl = (isY ? Yl : Xl) + rr * 16;
    float s = 0.f;
    #pragma unroll
    for (int k4 = 0; k4 < 16; ++k4) {
        float4 v = Rg[k4];
        ushort4 h, l;
        h.x = f32_bf16_rne(v.x); l.x = f32_bf16_rne(v.x - bf16_f32(h.x));
        h.y = f32_bf16_rne(v.y); l.y = f32_bf16_rne(v.y - bf16_f32(h.y));
        h.z = f32_bf16_rne(v.z); l.z = f32_bf16_rne(v.z - bf16_f32(h.z));
        h.w = f32_bf16_rne(v.w); l.w = f32_bf16_rne(v.w - bf16_f32(h.w));
        Hh[k4] = h; Hl[k4] = l;
        s = fmaf(v.x, v.x, s); s = fmaf(v.y, v.y, s);
        s = fmaf(v.z, v.z, s); s = fmaf(v.w, v.w, s);
    }
    if (isY) ny[rr] = s; else nx[rr] = s;
}

// ---- main tile kernel, compacted grid (65,64,2):
//      blockIdx.z==1 -> xy tiles (gi<64); z==0 -> triangle-pair packing of
//      xx (gi>gj) and yy (gi<=gj), always bx>=by. Off-diagonal tiles also
//      emit the mirror tile's leaf sums as column chains (bitwise-symmetric
//      kernel matrix).
__global__ __launch_bounds__(512, 4) void mmd_tile_kernel(
    const unsigned short* __restrict__ Xh, const unsigned short* __restrict__ Xl,
    const unsigned short* __restrict__ Yh, const unsigned short* __restrict__ Yl,
    const float* __restrict__ nx, const float* __restrict__ ny,
    float* __restrict__ leafs)
{
    const int gi = blockIdx.x;             // 0..64
    const int gj = blockIdx.y;             // 0..63
    int zz, bx, by;
    if (blockIdx.z == 1) {
        if (gi >= 64) return;              // 64 null blocks only
        zz = 2; bx = gi; by = gj;
    } else if (gi > gj) {
        zz = 0; by = gj; bx = gi - 1;      // xx upper triangle incl diag
    } else {
        zz = 1; by = gi; bx = gj;          // yy upper triangle incl diag
    }

    __shared__ __align__(16) unsigned short smem[4 * BT * RSTR];  // 73728 B
    __shared__ float sqA[BT];
    __shared__ float sqB[BT];

    unsigned short* Ah = smem;
    unsigned short* Al = smem + 1 * BT * RSTR;
    unsigned short* Bh = smem + 2 * BT * RSTR;
    unsigned short* Bl = smem + 3 * BT * RSTR;
    float* Ks = (float*)smem;     // [128][KSTR] floats, aliases the bf16 tiles

    const int t = threadIdx.x;
    const size_t arow = (size_t)by * BT;
    const size_t brow = (size_t)bx * BT;
    const int cb = bx;

    const unsigned short* gAh = ((zz == 1) ? Yh : Xh) + arow * DIM;
    const unsigned short* gAl = ((zz == 1) ? Yl : Xl) + arow * DIM;
    const unsigned short* gBh = ((zz == 0) ? Xh : Yh) + brow * DIM;
    const unsigned short* gBl = ((zz == 0) ? Xl : Yl) + brow * DIM;

    // ---- staging: pure ushort8 copy, 8 chunks/thread
    {
        const unsigned short* gs[4] = {gAh, gAl, gBh, gBl};
        unsigned short* ld[4] = {Ah, Al, Bh, Bl};
        #pragma unroll
        for (int a = 0; a < 4; ++a)
            #pragma unroll
            for (int half = 0; half < 2; ++half) {
                int idx = half * 512 + t;        // 0..1023
                int r   = idx >> 3;
                int k8  = idx & 7;
                *(ushort8v*)(ld[a] + r * RSTR + k8 * 8) =
                    *(const ushort8v*)(gs[a] + r * DIM + k8 * 8);
            }
    }

    // ---- norms: load precomputed
    if (t < 256) {
        const float* nA = (zz == 1) ? ny : nx;
        const float* nB = (zz == 0) ? nx : ny;
        if (t < BT) sqA[t] = nA[arow + t];
        else        sqB[t - BT] = nB[brow + t - BT];
    }
    __syncthreads();

    // ---- MFMA main: wave -> 32x64 sub-tile (2 row-tiles x 4 col-tiles)
    const int lane = t & 63;
    const int wv   = t >> 6;               // 0..7
    const int mrow = lane & 15;
    const int quad = lane >> 4;
    const int rblk = (wv & 3) << 5;        // 0,32,64,96
    const int cblk = (wv >> 2) << 6;       // 0,64

    bf16x8 fAh[2][2], fAl[2][2];
    #pragma unroll
    for (int rt = 0; rt < 2; ++rt)
        #pragma unroll
        for (int kc = 0; kc < 2; ++kc) {
            const unsigned short* p = Ah + (rblk + rt * 16 + mrow) * RSTR + kc * 32 + quad * 8;
            fAh[rt][kc] = *(const bf16x8*)p;
            fAl[rt][kc] = *(const bf16x8*)(p + BT * RSTR);
        }

    f32x4 acc[2][4];
    #pragma unroll
    for (int rt = 0; rt < 2; ++rt)
        #pragma unroll
        for (int ct = 0; ct < 4; ++ct)
            acc[rt][ct] = (f32x4){0.f, 0.f, 0.f, 0.f};

    #pragma unroll
    for (int ct = 0; ct < 4; ++ct) {
        const unsigned short* q = Bh + (cblk + ct * 16 + mrow) * RSTR + quad * 8;
        bf16x8 bh0 = *(const bf16x8*)(q);
        bf16x8 bh1 = *(const bf16x8*)(q + 32);
        bf16x8 bl0 = *(const bf16x8*)(q + BT * RSTR);
        bf16x8 bl1 = *(const bf16x8*)(q + BT * RSTR + 32);
        #pragma unroll
        for (int rt = 0; rt < 2; ++rt) {
            f32x4 c = acc[rt][ct];
            // identical 6-pass order per accumulator as R8-R11
            c = __builtin_amdgcn_mfma_f32_16x16x32_bf16(fAh[rt][0], bh0, c, 0, 0, 0);
            c = __builtin_amdgcn_mfma_f32_16x16x32_bf16(fAh[rt][0], bl0, c, 0, 0, 0);
            c = __builtin_amdgcn_mfma_f32_16x16x32_bf16(fAl[rt][0], bh0, c, 0, 0, 0);
            c = __builtin_amdgcn_mfma_f32_16x16x32_bf16(fAh[rt][1], bh1, c, 0, 0, 0);
            c = __builtin_amdgcn_mfma_f32_16x16x32_bf16(fAh[rt][1], bl1, c, 0, 0, 0);
            c = __builtin_amdgcn_mfma_f32_16x16x32_bf16(fAl[rt][1], bh1, c, 0, 0, 0);
            acc[rt][ct] = c;
        }
    }
    __syncthreads();   // all frag reads done; Ks may overwrite tiles

    // ---- epilogue: k = exp2f(sqd * -log2e/4096) — R5/R6's exact formula
    //      (native v_exp_f32; absmax proven identical across exp variants)
    const float SCL = (float)(-1.4426950408889634 / 4096.0);
    #pragma unroll
    for (int rt = 0; rt < 2; ++rt)
        #pragma unroll
        for (int ct = 0; ct < 4; ++ct)
            #pragma unroll
            for (int i = 0; i < 4; ++i) {
                int row = rblk + rt * 16 + quad * 4 + i;
                int col = cblk + ct * 16 + mrow;
                float d  = acc[rt][ct][i];
                float s2 = sqA[row] + sqB[col];
                float sqd = s2 - 2.0f * d;
                Ks[row * KSTR + col] = exp2f(sqd * SCL);
            }
    __syncthreads();

    // ---- numpy leaf sums, row chains (identical to R10/R11)
    float leaf[2];
    #pragma unroll
    for (int j = 0; j < 2; ++j) {
        int ch  = t + 512 * j;        // chain id 0..1023
        int row = ch >> 3;
        int tt  = ch & 7;
        float s = Ks[row * KSTR + tt];
        #pragma unroll
        for (int q = 1; q < 16; ++q) s += Ks[row * KSTR + tt + 8 * q];
        float p;
        p = __shfl_xor(s, 1); s = s + p;
        p = __shfl_xor(s, 2); s = s + p;
        p = __shfl_xor(s, 4); s = s + p;
        leaf[j] = s;
    }
    if ((t & 7) == 0) {
        int rb = t >> 3;              // 0..63
        #pragma unroll
        for (int j = 0; j < 2; ++j) {
            int row = rb + 64 * j;
            leafs[((size_t)zz * 8192 + arow + row) * 64 + cb] = leaf[j];
        }
    }

    // ---- mirror tile's leaf sums (zz<2, strict off-diagonal): column chains
    if (zz < 2 && bx > by) {
        float mleaf[2];
        #pragma unroll
        for (int j = 0; j < 2; ++j) {
            int ch  = t + 512 * j;    // chain id 0..1023
            int c   = ch >> 3;        // mirror-row = our column
            int tt  = ch & 7;
            float s = Ks[tt * KSTR + c];
            #pragma unroll
            for (int q = 1; q < 16; ++q) s += Ks[(tt + 8 * q) * KSTR + c];
            float p;
            p = __shfl_xor(s, 1); s = s + p;
            p = __shfl_xor(s, 2); s = s + p;
            p = __shfl_xor(s, 4); s = s + p;
            mleaf[j] = s;
        }
        if ((t & 7) == 0) {
            int rb = t >> 3;          // 0..63
            #pragma unroll
            for (int j = 0; j < 2; ++j) {
                int row = rb + 64 * j;            // mirror-row within tile
                leafs[((size_t)zz * 8192 + brow + row) * 64 + by] = mleaf[j];
            }
        }
    }
}

// Phase B: per row, balanced binary tree over its 64 leaf sums
__global__ void rowsum_kernel(const float* __restrict__ leafs, float* __restrict__ rowsums) {
    int tid = blockIdx.x * 256 + threadIdx.x;
    const float4* p = (const float4*)(leafs + (size_t)tid * 64);
    float v[64];
    #pragma unroll
    for (int i = 0; i < 16; ++i) {
        float4 q = p[i];
        v[4*i+0] = q.x; v[4*i+1] = q.y; v[4*i+2] = q.z; v[4*i+3] = q.w;
    }
    #pragma unroll
    for (int n = 32; n >= 1; n >>= 1)
        #pragma unroll
        for (int i = 0; i < 64; ++i)
            if (i < n) v[i] = v[2*i] + v[2*i+1];
    rowsums[tid] = v[0];
}

// Phase C: per matrix, balanced tree over 8192 row sums; /2^26 exact.
// Thread j's 5-level register subtree over elements [32j,32j+32) pairs
// exactly like the iterative halving (32 | boundaries) -> bit-identical.
__global__ void colsum_kernel(const float* __restrict__ rowsums, float* __restrict__ means) {
    __shared__ float L[256];
    const int z = blockIdx.x;
    const int t = threadIdx.x;
    const float4* src = (const float4*)(rowsums + z * 8192);
    float v[32];
    #pragma unroll
    for (int i = 0; i < 8; ++i) {
        float4 q = src[t * 8 + i];
        v[4*i+0] = q.x; v[4*i+1] = q.y; v[4*i+2] = q.z; v[4*i+3] = q.w;
    }
    #pragma unroll
    for (int n = 16; n >= 1; n >>= 1)
        #pragma unroll
        for (int i = 0; i < 32; ++i)
            if (i < n) v[i] = v[2*i] + v[2*i+1];
    L[t] = v[0];
    __syncthreads();
    for (int n = 128; n >= 1; n >>= 1) {
        float w = 0.f;
        if (t < n) w = L[2*t] + L[2*t+1];
        __syncthreads();
        if (t < n) L[t] = w;
        __syncthreads();
    }
    if (t == 0) means[z] = L[0] * (1.0f / 67108864.0f);
}

// Phase D: fp32 combine in reference expression order
__global__ void combine_kernel(const float* __restrict__ means, float* __restrict__ out) {
    float t1 = means[0] + means[1];
    out[0] = t1 - 2.0f * means[2];
}

extern "C" void kernel_launch(void* const* d_in, const int* in_sizes, int n_in,
                              void* d_out, int out_size, void* d_ws, size_t ws_size,
                              hipStream_t stream) {
    const float* x = (const float*)d_in[0];
    const float* y = (const float*)d_in[1];
    float* wsf     = (float*)d_ws;
    float* leafs   = wsf + LEAF_F;
    float* rowsums = wsf + ROWS_F;
    float* means   = wsf + MEANS_F;
    float* nx      = wsf + NX_F;
    float* ny      = wsf + NY_F;
    unsigned short* Xh = (unsigned short*)(wsf + SPLIT_F);
    unsigned short* Xl = Xh + SPLIT_ELEMS;
    unsigned short* Yh = Xl + SPLIT_ELEMS;
    unsigned short* Yl = Yh + SPLIT_ELEMS;

    prep_kernel<<<64, 256, 0, stream>>>(x, y,
                                        (ushort4*)Xh, (ushort4*)Xl,
                                        (ushort4*)Yh, (ushort4*)Yl, nx, ny);
    dim3 grid(65, 64, 2);
    mmd_tile_kernel<<<grid, 512, 0, stream>>>(Xh, Xl, Yh, Yl, nx, ny, leafs);
    rowsum_kernel<<<(3 * 8192) / 256, 256, 0, stream>>>(leafs, rowsums);
    colsum_kernel<<<3, 256, 0, stream>>>(rowsums, means);
    combine_kernel<<<1, 1, 0, stream>>>(means, (float*)d_out);
}

// Round 13
// 156.446 us; speedup vs baseline: 3.1445x; 1.0979x over previous
//
#include <hip/hip_runtime.h>
#include <cmath>

#define NPTS 8192
#define DIM 64
#define BT 128
#define KSTR 132         // float word stride for Ks rows

// ws layout (float offsets)
#define LEAF_F   0
#define LEAF_N   (3 * 8192 * 64)          // 1572864
#define ROWS_F   (LEAF_F + LEAF_N)
#define ROWS_N   (3 * 8192)
#define MEANS_F  (ROWS_F + ROWS_N)
#define NX_F     ((MEANS_F + 3 + 3) & ~3) // 16B-align
#define NY_F     (NX_F + 8192)
#define SPLIT_F  (NY_F + 8192)            // ushort arrays start here (16B-aligned)
#define SPLIT_ELEMS (NPTS * DIM)          // 524288 ushorts per array

// frag-major split layout: [rowtile t16][kc 0..1][quad 0..3][mrow 0..15][8]
// addr(t16,kc,quad,mrow) = t16*1024 + kc*512 + quad*128 + mrow*8  (ushorts)

typedef short bf16x8 __attribute__((ext_vector_type(8)));
typedef float f32x4  __attribute__((ext_vector_type(4)));

__device__ __forceinline__ unsigned short f32_bf16_rne(float f) {
    unsigned u = __float_as_uint(f);
    return (unsigned short)((u + 0x7FFFu + ((u >> 16) & 1u)) >> 16);
}
__device__ __forceinline__ float bf16_f32(unsigned short h) {
    return __uint_as_float(((unsigned)h) << 16);
}

// ---- fused prep: bf16 hi/lo RNE split (frag-major layout) + row norms.
//      Split/norm chains identical to R12; only the store addresses changed.
__global__ void prep_kernel(const float* __restrict__ x, const float* __restrict__ y,
                            unsigned short* __restrict__ Xh, unsigned short* __restrict__ Xl,
                            unsigned short* __restrict__ Yh, unsigned short* __restrict__ Yl,
                            float* __restrict__ nx, float* __restrict__ ny) {
    int r = blockIdx.x * 256 + threadIdx.x;   // 0..16383
    int isY = r >= NPTS;
    int rr = isY ? r - NPTS : r;
    const float4* Rg = (const float4*)((isY ? y : x) + (size_t)rr * DIM);
    unsigned short* Hh = isY ? Yh : Xh;
    unsigned short* Hl = isY ? Yl : Xl;
    const int t16 = rr >> 4, mrow = rr & 15;
    float s = 0.f;
    #pragma unroll
    for (int k4 = 0; k4 < 16; ++k4) {
        float4 v = Rg[k4];
        ushort4 h, l;
        h.x = f32_bf16_rne(v.x); l.x = f32_bf16_rne(v.x - bf16_f32(h.x));
        h.y = f32_bf16_rne(v.y); l.y = f32_bf16_rne(v.y - bf16_f32(h.y));
        h.z = f32_bf16_rne(v.z); l.z = f32_bf16_rne(v.z - bf16_f32(h.z));
        h.w = f32_bf16_rne(v.w); l.w = f32_bf16_rne(v.w - bf16_f32(h.w));
        int off = t16 * 1024 + (k4 >> 3) * 512 + ((k4 >> 1) & 3) * 128 + mrow * 8 + (k4 & 1) * 4;
        *(ushort4*)(Hh + off) = h;
        *(ushort4*)(Hl + off) = l;
        s = fmaf(v.x, v.x, s); s = fmaf(v.y, v.y, s);
        s = fmaf(v.z, v.z, s); s = fmaf(v.w, v.w, s);
    }
    if (isY) ny[rr] = s; else nx[rr] = s;
}

// ---- main tile kernel, compacted grid (65,64,2); fragments loaded DIRECTLY
//      from global (frag-major layout, 1KB coalesced bursts) — no LDS staging.
//      LDS holds only Ks + norms. All arithmetic chains identical to R12.
__global__ __launch_bounds__(512, 4) void mmd_tile_kernel(
    const unsigned short* __restrict__ Xh, const unsigned short* __restrict__ Xl,
    const unsigned short* __restrict__ Yh, const unsigned short* __restrict__ Yl,
    const float* __restrict__ nx, const float* __restrict__ ny,
    float* __restrict__ leafs)
{
    const int gi = blockIdx.x;             // 0..64
    const int gj = blockIdx.y;             // 0..63
    int zz, bx, by;
    if (blockIdx.z == 1) {
        if (gi >= 64) return;              // 64 null blocks only
        zz = 2; bx = gi; by = gj;
    } else if (gi > gj) {
        zz = 0; by = gj; bx = gi - 1;      // xx upper triangle incl diag
    } else {
        zz = 1; by = gi; bx = gj;          // yy upper triangle incl diag
    }

    __shared__ float Ks[128 * KSTR];       // 67584 B
    __shared__ float sqA[BT];
    __shared__ float sqB[BT];

    const int t = threadIdx.x;
    const size_t arow = (size_t)by * BT;
    const size_t brow = (size_t)bx * BT;
    const int cb = bx;

    const unsigned short* pAh = (zz == 1) ? Yh : Xh;
    const unsigned short* pAl = (zz == 1) ? Yl : Xl;
    const unsigned short* pBh = (zz == 0) ? Xh : Yh;
    const unsigned short* pBl = (zz == 0) ? Xl : Yl;

    // ---- norms: load precomputed
    if (t < 256) {
        const float* nA = (zz == 1) ? ny : nx;
        const float* nB = (zz == 0) ? nx : ny;
        if (t < BT) sqA[t] = nA[arow + t];
        else        sqB[t - BT] = nB[brow + t - BT];
    }
    __syncthreads();

    // ---- MFMA main: wave -> 32x64 sub-tile (2 row-tiles x 4 col-tiles)
    const int lane = t & 63;
    const int wv   = t >> 6;               // 0..7
    const int mrow = lane & 15;
    const int quad = lane >> 4;
    const int rblk = (wv & 3) << 5;        // 0,32,64,96
    const int cblk = (wv >> 2) << 6;       // 0,64

    const int aT = by * 8 + (wv & 3) * 2;  // row-tile index base for this wave
    const int bT = bx * 8 + (wv >> 2) * 4; // col-tile index base
    const int lsub = quad * 128 + mrow * 8;

    bf16x8 fAh[2][2], fAl[2][2];
    #pragma unroll
    for (int rt = 0; rt < 2; ++rt)
        #pragma unroll
        for (int kc = 0; kc < 2; ++kc) {
            int off = (aT + rt) * 1024 + kc * 512 + lsub;
            fAh[rt][kc] = *(const bf16x8*)(pAh + off);
            fAl[rt][kc] = *(const bf16x8*)(pAl + off);
        }

    f32x4 acc[2][4];
    #pragma unroll
    for (int rt = 0; rt < 2; ++rt)
        #pragma unroll
        for (int ct = 0; ct < 4; ++ct)
            acc[rt][ct] = (f32x4){0.f, 0.f, 0.f, 0.f};

    #pragma unroll
    for (int ct = 0; ct < 4; ++ct) {
        int boff = (bT + ct) * 1024 + lsub;
        bf16x8 bh0 = *(const bf16x8*)(pBh + boff);
        bf16x8 bh1 = *(const bf16x8*)(pBh + boff + 512);
        bf16x8 bl0 = *(const bf16x8*)(pBl + boff);
        bf16x8 bl1 = *(const bf16x8*)(pBl + boff + 512);
        #pragma unroll
        for (int rt = 0; rt < 2; ++rt) {
            f32x4 c = acc[rt][ct];
            // identical 6-pass order per accumulator as R8-R12
            c = __builtin_amdgcn_mfma_f32_16x16x32_bf16(fAh[rt][0], bh0, c, 0, 0, 0);
            c = __builtin_amdgcn_mfma_f32_16x16x32_bf16(fAh[rt][0], bl0, c, 0, 0, 0);
            c = __builtin_amdgcn_mfma_f32_16x16x32_bf16(fAl[rt][0], bh0, c, 0, 0, 0);
            c = __builtin_amdgcn_mfma_f32_16x16x32_bf16(fAh[rt][1], bh1, c, 0, 0, 0);
            c = __builtin_amdgcn_mfma_f32_16x16x32_bf16(fAh[rt][1], bl1, c, 0, 0, 0);
            c = __builtin_amdgcn_mfma_f32_16x16x32_bf16(fAl[rt][1], bh1, c, 0, 0, 0);
            acc[rt][ct] = c;
        }
    }

    // ---- epilogue: k = exp2f(sqd * -log2e/4096) (identical to R12)
    const float SCL = (float)(-1.4426950408889634 / 4096.0);
    #pragma unroll
    for (int rt = 0; rt < 2; ++rt)
        #pragma unroll
        for (int ct = 0; ct < 4; ++ct)
            #pragma unroll
            for (int i = 0; i < 4; ++i) {
                int row = rblk + rt * 16 + quad * 4 + i;
                int col = cblk + ct * 16 + mrow;
                float d  = acc[rt][ct][i];
                float s2 = sqA[row] + sqB[col];
                float sqd = s2 - 2.0f * d;
                Ks[row * KSTR + col] = exp2f(sqd * SCL);
            }
    __syncthreads();

    // ---- numpy leaf sums, row chains (identical to R10-R12)
    float leaf[2];
    #pragma unroll
    for (int j = 0; j < 2; ++j) {
        int ch  = t + 512 * j;        // chain id 0..1023
        int row = ch >> 3;
        int tt  = ch & 7;
        float s = Ks[row * KSTR + tt];
        #pragma unroll
        for (int q = 1; q < 16; ++q) s += Ks[row * KSTR + tt + 8 * q];
        float p;
        p = __shfl_xor(s, 1); s = s + p;
        p = __shfl_xor(s, 2); s = s + p;
        p = __shfl_xor(s, 4); s = s + p;
        leaf[j] = s;
    }
    if ((t & 7) == 0) {
        int rb = t >> 3;              // 0..63
        #pragma unroll
        for (int j = 0; j < 2; ++j) {
            int row = rb + 64 * j;
            leafs[((size_t)zz * 8192 + arow + row) * 64 + cb] = leaf[j];
        }
    }

    // ---- mirror tile's leaf sums (zz<2, strict off-diagonal): column chains
    if (zz < 2 && bx > by) {
        float mleaf[2];
        #pragma unroll
        for (int j = 0; j < 2; ++j) {
            int ch  = t + 512 * j;    // chain id 0..1023
            int c   = ch >> 3;        // mirror-row = our column
            int tt  = ch & 7;
            float s = Ks[tt * KSTR + c];
            #pragma unroll
            for (int q = 1; q < 16; ++q) s += Ks[(tt + 8 * q) * KSTR + c];
            float p;
            p = __shfl_xor(s, 1); s = s + p;
            p = __shfl_xor(s, 2); s = s + p;
            p = __shfl_xor(s, 4); s = s + p;
            mleaf[j] = s;
        }
        if ((t & 7) == 0) {
            int rb = t >> 3;          // 0..63
            #pragma unroll
            for (int j = 0; j < 2; ++j) {
                int row = rb + 64 * j;            // mirror-row within tile
                leafs[((size_t)zz * 8192 + brow + row) * 64 + by] = mleaf[j];
            }
        }
    }
}

// Phase B: per row, balanced binary tree over its 64 leaf sums
__global__ void rowsum_kernel(const float* __restrict__ leafs, float* __restrict__ rowsums) {
    int tid = blockIdx.x * 256 + threadIdx.x;
    const float4* p = (const float4*)(leafs + (size_t)tid * 64);
    float v[64];
    #pragma unroll
    for (int i = 0; i < 16; ++i) {
        float4 q = p[i];
        v[4*i+0] = q.x; v[4*i+1] = q.y; v[4*i+2] = q.z; v[4*i+3] = q.w;
    }
    #pragma unroll
    for (int n = 32; n >= 1; n >>= 1)
        #pragma unroll
        for (int i = 0; i < 64; ++i)
            if (i < n) v[i] = v[2*i] + v[2*i+1];
    rowsums[tid] = v[0];
}

// Phase C: per matrix, balanced tree over 8192 row sums; /2^26 exact.
__global__ void colsum_kernel(const float* __restrict__ rowsums, float* __restrict__ means) {
    __shared__ float L[256];
    const int z = blockIdx.x;
    const int t = threadIdx.x;
    const float4* src = (const float4*)(rowsums + z * 8192);
    float v[32];
    #pragma unroll
    for (int i = 0; i < 8; ++i) {
        float4 q = src[t * 8 + i];
        v[4*i+0] = q.x; v[4*i+1] = q.y; v[4*i+2] = q.z; v[4*i+3] = q.w;
    }
    #pragma unroll
    for (int n = 16; n >= 1; n >>= 1)
        #pragma unroll
        for (int i = 0; i < 32; ++i)
            if (i < n) v[i] = v[2*i] + v[2*i+1];
    L[t] = v[0];
    __syncthreads();
    for (int n = 128; n >= 1; n >>= 1) {
        float w = 0.f;
        if (t < n) w = L[2*t] + L[2*t+1];
        __syncthreads();
        if (t < n) L[t] = w;
        __syncthreads();
    }
    if (t == 0) means[z] = L[0] * (1.0f / 67108864.0f);
}

// Phase D: fp32 combine in reference expression order
__global__ void combine_kernel(const float* __restrict__ means, float* __restrict__ out) {
    float t1 = means[0] + means[1];
    out[0] = t1 - 2.0f * means[2];
}

extern "C" void kernel_launch(void* const* d_in, const int* in_sizes, int n_in,
                              void* d_out, int out_size, void* d_ws, size_t ws_size,
                              hipStream_t stream) {
    const float* x = (const float*)d_in[0];
    const float* y = (const float*)d_in[1];
    float* wsf     = (float*)d_ws;
    float* leafs   = wsf + LEAF_F;
    float* rowsums = wsf + ROWS_F;
    float* means   = wsf + MEANS_F;
    float* nx      = wsf + NX_F;
    float* ny      = wsf + NY_F;
    unsigned short* Xh = (unsigned short*)(wsf + SPLIT_F);
    unsigned short* Xl = Xh + SPLIT_ELEMS;
    unsigned short* Yh = Xl + SPLIT_ELEMS;
    unsigned short* Yl = Yh + SPLIT_ELEMS;

    prep_kernel<<<64, 256, 0, stream>>>(x, y, Xh, Xl, Yh, Yl, nx, ny);
    dim3 grid(65, 64, 2);
    mmd_tile_kernel<<<grid, 512, 0, stream>>>(Xh, Xl, Yh, Yl, nx, ny, leafs);
    rowsum_kernel<<<(3 * 8192) / 256, 256, 0, stream>>>(leafs, rowsums);
    colsum_kernel<<<3, 256, 0, stream>>>(rowsums, means);
    combine_kernel<<<1, 1, 0, stream>>>(means, (float*)d_out);
}